// Round 6
// baseline (5550.816 us; speedup 1.0000x reference)
//
#include <hip/hip_runtime.h>
#include <hip/hip_bf16.h>
#include <math.h>

// ---------------------------------------------------------------------------
// SecretRQVAE. d_out FLOAT32. Inputs runtime-sniffed (bf16 vs f32).
// Outputs (f32): recon[3145728] | indices[262144] | loss[4] | q_chw[16777216]
// Workspace (128 MB): PA [0,64MB): h1 -> h3 -> D1(lower 32MB); small bufs at
// +48MB and cbT/wd2t/zp2 at +36..40MB (live only post-conv4).
// PB [64,128MB): h2 -> z/res [d][n] -> D2.
//
// R10 counters: k_deconv1n 985us, VALUBusy 14%, WRITE_SIZE 557MB for a 64MB
// output (8.7x), FETCH 132MB (75MB = output RMW reads). Cause: epilogue does
// 64 scalar stride-2 stores/thread (parity interleave) -> 16.8M scattered
// dwords x 32B sector = 537MB ~= measured. deconv2n has the same pattern.
// R11: LDS-transpose epilogues. deconv1n: per-wave 64x36 padded tile (write
// banks 2-way=free), read back row-major float4 -> 8 coalesced 128B-segment
// stores per lane per half. deconv2n: block-wide 48x68 tile + barrier.
// Values (relu/tanh) bit-identical; only store order/width changes.
// ---------------------------------------------------------------------------

#define DEVFN static __device__ __forceinline__
DEVFN float b2f(__hip_bfloat16 v){ return __bfloat162float(v); }
DEVFN float ldv(const float* p, long long i){ return p[i]; }
DEVFN float ldv(const __hip_bfloat16* p, long long i){ return b2f(p[i]); }

DEVFN bool sniff_f32(const void* p){
  const unsigned* u = (const unsigned*)p;
  int hits = 0;
  #pragma unroll
  for (int i=0;i<64;i++){
    unsigned b = (u[i]>>7)&0xFFu;
    hits += (b>=118u && b<=134u) ? 1 : 0;
  }
  return hits < 32;
}

// async global->LDS; l must be wave-uniform, g per-lane.
DEVFN void gl_lds16(const float* g, float* l){
  __builtin_amdgcn_global_load_lds(
      (const __attribute__((address_space(1))) void*)g,
      (__attribute__((address_space(3))) void*)l, 16, 0, 0);
}
DEVFN void gl_lds4(const float* g, float* l){
  __builtin_amdgcn_global_load_lds(
      (const __attribute__((address_space(1))) void*)g,
      (__attribute__((address_space(3))) void*)l, 4, 0, 0);
}

// ============================ zero page init ================================
__global__ __launch_bounds__(64) void k_zero(float* zp)
{
  zp[threadIdx.x] = 0.f;
}

// ============================ conv1: 3->64, 4x4 s2 p1, relu ==================
template<class T>
DEVFN void conv1n_impl(const T* __restrict__ x, const T* __restrict__ w,
                       const T* __restrict__ bias, float* __restrict__ out,
                       float* lin, float* lw, float* lb)
{
  const int tid = threadIdx.x;
  const int tx = blockIdx.x & 3, ty = blockIdx.x >> 2;   // 4 x-tiles, 16 y-tiles
  const int b = blockIdx.y;
  for (int j = tid; j < 3072; j += 256){
    int co = j & 63, tt = j >> 6;                        // tt = cc*16+tap
    int cc = tt >> 4, tap = tt & 15;
    lw[j] = ldv(w, (co*3+cc)*16 + tap);
  }
  if (tid < 64) lb[tid] = ldv(bias, tid);
  const int oy0 = ty*8, ox0 = tx*32;
  const int iy0 = 2*oy0 - 1, ix0 = 2*ox0 - 1;
  for (int j = tid; j < 3564; j += 256){                 // 3cc x 18r x 66c
    int cc = j / 1188, rem = j - cc*1188;
    int r = rem / 66, cx = rem - r*66;
    int iy = iy0 + r, ix = ix0 + cx;
    float v = 0.f;
    if ((unsigned)iy < 256u && (unsigned)ix < 256u)
      v = ldv(x, (long long)b*196608 + (cc*256+iy)*256 + ix);
    lin[j] = v;
  }
  __syncthreads();
  const int pxg = tid & 31, cog = tid >> 5;
  const int y = pxg >> 2, xb = (pxg & 3) << 3;
  float acc[8][8];
  #pragma unroll
  for (int i=0;i<8;i++)
    #pragma unroll
    for (int j=0;j<8;j++) acc[i][j] = lb[cog*8+j];
  #pragma unroll 1
  for (int cc=0; cc<3; cc++){
    #pragma unroll
    for (int ky=0; ky<4; ky++){
      const float* rowp = &lin[(cc*18 + 2*y+ky)*66 + 2*xb];
      float a[18];
      #pragma unroll
      for (int t=0; t<9; t++) *(float2*)&a[2*t] = *(const float2*)&rowp[2*t];
      #pragma unroll
      for (int kx=0; kx<4; kx++){
        const float* wp = &lw[(cc*16 + ky*4+kx)*64 + cog*8];
        float wv[8];
        *(float4*)&wv[0] = *(const float4*)&wp[0];
        *(float4*)&wv[4] = *(const float4*)&wp[4];
        #pragma unroll
        for (int j=0;j<8;j++)
          #pragma unroll
          for (int i=0;i<8;i++)
            acc[i][j] += a[2*i+kx]*wv[j];
      }
    }
  }
  #pragma unroll
  for (int j=0;j<8;j++){
    const int co = cog*8 + j;
    float4 v0, v1;
    v0.x = fmaxf(acc[0][j],0.f); v0.y = fmaxf(acc[1][j],0.f);
    v0.z = fmaxf(acc[2][j],0.f); v0.w = fmaxf(acc[3][j],0.f);
    v1.x = fmaxf(acc[4][j],0.f); v1.y = fmaxf(acc[5][j],0.f);
    v1.z = fmaxf(acc[6][j],0.f); v1.w = fmaxf(acc[7][j],0.f);
    long long base = ((long long)(b*64 + co)*128 + oy0+y)*128 + ox0+xb;
    *(float4*)&out[base]   = v0;
    *(float4*)&out[base+4] = v1;
  }
}

__global__ __launch_bounds__(256, 4) void k_conv1n(const void* x, const void* w,
    const void* bias, float* out)
{
  __shared__ __align__(16) float lin[3564];
  __shared__ __align__(16) float lw[3072];
  __shared__ float lb[64];
  if (sniff_f32(w)) conv1n_impl((const float*)x, (const float*)w, (const float*)bias, out, lin, lw, lb);
  else conv1n_impl((const __hip_bfloat16*)x, (const __hip_bfloat16*)w, (const __hip_bfloat16*)bias, out, lin, lw, lb);
}

// ===== weight transpose conv2: [co128][ci64][16] -> [cg2][ch32][cc*16+tap][64co]
template<class T>
DEVFN void wtr2_impl(const T* __restrict__ w, const T* __restrict__ bias,
                     float* __restrict__ o)
{
  int gid = blockIdx.x*256 + threadIdx.x;
  if (gid < 131072){
    int co = gid & 63;
    int g6 = gid >> 6;
    int t  = g6 & 31;            // cc*16 + tap
    int q  = g6 >> 5;            // cg*32 + ch
    int cg = q >> 5, ch = q & 31;
    int cc = t >> 4, tap = t & 15;
    o[gid] = ldv(w, ((cg*64+co)*64 + ch*2+cc)*16 + tap);
  } else if (gid < 131200){
    o[gid] = ldv(bias, gid - 131072);
  }
}

__global__ __launch_bounds__(256) void k_wtr2(const void* w, const void* bias, float* o)
{
  if (sniff_f32(w)) wtr2_impl((const float*)w, (const float*)bias, o);
  else wtr2_impl((const __hip_bfloat16*)w, (const __hip_bfloat16*)bias, o);
}

// ============================ conv2: 64->128, 4x4 s2 p1, relu ================
__global__ __launch_bounds__(256, 4) void k_conv2n(const float* __restrict__ in,
    const float* __restrict__ wtr, const float* __restrict__ zp,
    float* __restrict__ out)
{
  __shared__ __align__(16) float lin[2][2432];   // 2cc x 18r x 66c (+pad)
  __shared__ __align__(16) float lw[2][2048];    // 2cc x 16tap x 64co
  __shared__ float lb[64];
  const int tid = threadIdx.x;
  const int tx = blockIdx.x & 1, ty = blockIdx.x >> 1;
  const int b = blockIdx.y, cg = blockIdx.z;
  if (tid < 64) lb[tid] = wtr[131072 + cg*64 + tid];
  const int pxg = tid & 31, cog = tid >> 5;
  const int y = pxg >> 2, xb = (pxg & 3) << 3;
  const int oy0 = ty*8, ox0 = tx*32;
  const int wave = tid >> 6, lane = tid & 63;
  const int wbase = wave*64;

  int goff[10];
  #pragma unroll
  for (int ii=0; ii<10; ii++){
    int j = tid + 256*ii;
    int cc = j / 1188, rem = j - cc*1188;
    int r = rem / 66, cx = rem - r*66;
    int iy = 2*oy0 - 1 + r, ix = 2*ox0 - 1 + cx;
    bool ok = (j < 2376) && ((unsigned)iy < 128u) && ((unsigned)ix < 128u);
    goff[ii] = ok ? (cc*16384 + iy*128 + ix) : -1;
  }
  const float* ib0 = in + (long long)b*1048576;
  const float* wb0 = wtr + cg*65536;

  #pragma unroll
  for (int ii=0; ii<10; ii++){
    int wb = wbase + 256*ii;
    if (wb < 2376)
      gl_lds4((goff[ii] >= 0) ? (ib0 + goff[ii]) : zp, &lin[0][wb]);
  }
  for (int c = wave; c < 8; c += 4)
    gl_lds16(wb0 + c*256 + lane*4, &lw[0][c*256]);
  __syncthreads();

  float acc[8][8];
  #pragma unroll
  for (int i=0;i<8;i++)
    #pragma unroll
    for (int j=0;j<8;j++) acc[i][j] = lb[cog*8+j];

  float* lin_c = lin[0]; float* lin_n = lin[1];
  float* lw_c  = lw[0];  float* lw_n  = lw[1];
  for (int k=0; k<32; k++){
    if (k+1 < 32){
      const float* ibk = ib0 + (k+1)*32768;
      const float* wn  = wb0 + (k+1)*2048;
      #pragma unroll
      for (int ii=0; ii<10; ii++){
        int wb = wbase + 256*ii;
        if (wb < 2376)
          gl_lds4((goff[ii] >= 0) ? (ibk + goff[ii]) : zp, lin_n + wb);
      }
      for (int c = wave; c < 8; c += 4)
        gl_lds16(wn + c*256 + lane*4, lw_n + c*256);
    }
    #pragma unroll 1
    for (int cc=0; cc<2; cc++){
      #pragma unroll
      for (int ky=0; ky<4; ky++){
        const float* rowp = &lin_c[(cc*18 + 2*y+ky)*66 + 2*xb];
        float a[18];
        #pragma unroll
        for (int t=0; t<9; t++) *(float2*)&a[2*t] = *(const float2*)&rowp[2*t];
        #pragma unroll
        for (int kx=0; kx<4; kx++){
          const float* wp = &lw_c[(cc*16 + ky*4+kx)*64 + cog*8];
          float wv[8];
          *(float4*)&wv[0] = *(const float4*)&wp[0];
          *(float4*)&wv[4] = *(const float4*)&wp[4];
          #pragma unroll
          for (int j=0;j<8;j++)
            #pragma unroll
            for (int i=0;i<8;i++)
              acc[i][j] += a[2*i+kx]*wv[j];
        }
      }
    }
    __syncthreads();
    float* t0 = lin_c; lin_c = lin_n; lin_n = t0;
    float* t1 = lw_c;  lw_c  = lw_n;  lw_n  = t1;
  }

  #pragma unroll
  for (int j=0;j<8;j++){
    const int co = cg*64 + cog*8 + j;
    float4 v0, v1;
    v0.x = fmaxf(acc[0][j],0.f); v0.y = fmaxf(acc[1][j],0.f);
    v0.z = fmaxf(acc[2][j],0.f); v0.w = fmaxf(acc[3][j],0.f);
    v1.x = fmaxf(acc[4][j],0.f); v1.y = fmaxf(acc[5][j],0.f);
    v1.z = fmaxf(acc[6][j],0.f); v1.w = fmaxf(acc[7][j],0.f);
    long long base = ((long long)(b*128 + co)*64 + oy0+y)*64 + ox0+xb;
    *(float4*)&out[base]   = v0;
    *(float4*)&out[base+4] = v1;
  }
}

// ============== weight transpose for 3x3 convs: -> [cg][ch][cc*9+tap][co] ====
template<int CO, int CI, class T>
DEVFN void wtr_impl(const T* __restrict__ w, const T* __restrict__ bias,
                    float* __restrict__ o)
{
  const int NW = CO*CI*9;
  int gid = blockIdx.x*256 + threadIdx.x;
  if (gid < NW){
    int co = gid & 63;
    int g6 = gid >> 6;
    int t  = g6 % 36;            // cc*9 + tap
    int q  = g6 / 36;            // cg*(CI/4) + ch
    const int NCH = CI/4;
    int cg = q / NCH, ch = q - cg*NCH;
    int cc = t / 9, tap = t - cc*9;
    o[gid] = ldv(w, ((long long)(cg*64+co)*CI + ch*4+cc)*9 + tap);
  } else if (gid < NW + CO){
    o[gid] = ldv(bias, gid - NW);
  }
}

template<int CO, int CI>
__global__ __launch_bounds__(256) void k_wtr(const void* w, const void* bias, float* o)
{
  if (sniff_f32(w)) wtr_impl<CO,CI>((const float*)w, (const float*)bias, o);
  else wtr_impl<CO,CI>((const __hip_bfloat16*)w, (const __hip_bfloat16*)bias, o);
}

// ============================ 3x3 s1 p1 conv (conv3/conv4/dec1) =============
template<int CI, bool RELU, bool OUT_T>
__global__ __launch_bounds__(256, 4) void k_conv3x3(const float* __restrict__ in,
    const float* __restrict__ wtr, const float* __restrict__ zp,
    float* __restrict__ out)
{
  __shared__ __align__(16) float lin[2][1408];   // 4cc x 10r x 34c (+tail pad)
  __shared__ __align__(16) float lw[2][2304];    // 4cc x 9tap x 64co
  __shared__ float lb[64];
  const int tid = threadIdx.x;
  const int tx = blockIdx.x & 1, ty = blockIdx.x >> 1;
  const int b = blockIdx.y, cg = blockIdx.z;
  const int CO = gridDim.z * 64;
  const int NCH = CI/4;
  const long long NW = (long long)CO*CI*9;
  if (tid < 64) lb[tid] = wtr[NW + cg*64 + tid];

  const int pxg = tid & 31, cog = tid >> 5;
  const int y = pxg >> 2, xb = (pxg & 3) << 3;
  const int oy0 = ty*8, ox0 = tx*32;
  const int wave = tid >> 6, lane = tid & 63;
  const int wbase = wave*64;

  int goff[6];
  #pragma unroll
  for (int ii=0; ii<6; ii++){
    int j = tid + 256*ii;
    int cc = j / 340, rem = j - cc*340;
    int r = rem / 34, cx = rem - r*34;
    int iy = oy0 - 1 + r, ix = ox0 - 1 + cx;
    bool ok = (j < 1360) && ((unsigned)iy < 64u) && ((unsigned)ix < 64u);
    goff[ii] = ok ? (cc*4096 + iy*64 + ix) : -1;
  }
  const float* ib0 = in + (long long)b*CI*4096;
  const float* wb0 = wtr + (long long)cg*NCH*2304;

  #pragma unroll
  for (int ii=0; ii<6; ii++){
    int wb = wbase + 256*ii;
    if (wb < 1360)
      gl_lds4((goff[ii] >= 0) ? (ib0 + goff[ii]) : zp, &lin[0][wb]);
  }
  for (int c = wave; c < 9; c += 4)
    gl_lds16(wb0 + c*256 + lane*4, &lw[0][c*256]);
  __syncthreads();

  float acc[8][8];
  #pragma unroll
  for (int i=0;i<8;i++)
    #pragma unroll
    for (int j=0;j<8;j++) acc[i][j] = lb[cog*8+j];

  float* lin_c = lin[0]; float* lin_n = lin[1];
  float* lw_c  = lw[0];  float* lw_n  = lw[1];
  for (int k=0; k<NCH; k++){
    if (k+1 < NCH){
      const float* ibk = ib0 + (long long)(k+1)*16384;
      const float* wn  = wb0 + (long long)(k+1)*2304;
      #pragma unroll
      for (int ii=0; ii<6; ii++){
        int wb = wbase + 256*ii;
        if (wb < 1360)
          gl_lds4((goff[ii] >= 0) ? (ibk + goff[ii]) : zp, lin_n + wb);
      }
      for (int c = wave; c < 9; c += 4)
        gl_lds16(wn + c*256 + lane*4, lw_n + c*256);
    }
    #pragma unroll 1
    for (int cc=0; cc<4; cc++){
      #pragma unroll
      for (int dy=0; dy<3; dy++){
        const float* rowp = &lin_c[(cc*10 + y+dy)*34 + xb];
        float a[10];
        *(float2*)&a[0] = *(const float2*)&rowp[0];
        *(float2*)&a[2] = *(const float2*)&rowp[2];
        *(float2*)&a[4] = *(const float2*)&rowp[4];
        *(float2*)&a[6] = *(const float2*)&rowp[6];
        *(float2*)&a[8] = *(const float2*)&rowp[8];
        #pragma unroll
        for (int dx=0; dx<3; dx++){
          const float* wp = &lw_c[(cc*9 + dy*3+dx)*64 + cog*8];
          float wv[8];
          *(float4*)&wv[0] = *(const float4*)&wp[0];
          *(float4*)&wv[4] = *(const float4*)&wp[4];
          #pragma unroll
          for (int j=0;j<8;j++)
            #pragma unroll
            for (int i=0;i<8;i++)
              acc[i][j] += a[i+dx]*wv[j];
        }
      }
    }
    __syncthreads();
    float* t0 = lin_c; lin_c = lin_n; lin_n = t0;
    float* t1 = lw_c;  lw_c  = lw_n;  lw_n  = t1;
  }

  const int oy = oy0 + y;
  #pragma unroll
  for (int j=0;j<8;j++){
    const int co = cg*64 + cog*8 + j;
    float4 v0, v1;
    v0.x = acc[0][j]; v0.y = acc[1][j]; v0.z = acc[2][j]; v0.w = acc[3][j];
    v1.x = acc[4][j]; v1.y = acc[5][j]; v1.z = acc[6][j]; v1.w = acc[7][j];
    if (RELU){
      v0.x = fmaxf(v0.x, 0.f); v0.y = fmaxf(v0.y, 0.f);
      v0.z = fmaxf(v0.z, 0.f); v0.w = fmaxf(v0.w, 0.f);
      v1.x = fmaxf(v1.x, 0.f); v1.y = fmaxf(v1.y, 0.f);
      v1.z = fmaxf(v1.z, 0.f); v1.w = fmaxf(v1.w, 0.f);
    }
    long long base = OUT_T ? ((long long)co*65536 + b*4096 + oy*64 + ox0+xb)
                           : (((long long)(b*CO + co)*64 + oy)*64 + ox0+xb);
    *(float4*)&out[base]   = v0;
    *(float4*)&out[base+4] = v1;
  }
}

// ================= codebook transpose: cb[q][k][d] -> cbT[q][d][k] ==========
template<class T>
DEVFN void cbt_impl(const T* __restrict__ cb, float* __restrict__ o,
                    float (*t)[65])
{
  const int k0 = blockIdx.x*64, d0 = blockIdx.y*64, q = blockIdx.z;
  const int tid = threadIdx.x;
  const int rr = tid >> 6, cc = tid & 63;
  #pragma unroll
  for (int p=0; p<16; p++){
    int kk = p*4 + rr;
    t[kk][cc] = ldv(cb, ((long long)(q*1024 + k0+kk))*256 + d0 + cc);
  }
  __syncthreads();
  #pragma unroll
  for (int p=0; p<16; p++){
    int dd = p*4 + rr;
    o[((long long)(q*256 + d0+dd))*1024 + k0 + cc] = t[cc][dd];
  }
}

__global__ __launch_bounds__(256) void k_cbt(const void* cb, float* o)
{
  __shared__ float t[64][65];
  if (sniff_f32(cb)) cbt_impl((const float*)cb, o, t);
  else cbt_impl((const __hip_bfloat16*)cb, o, t);
}

// ============================ codebook 0.5*||c||^2 ===========================
template<class T>
DEVFN void cnh_impl(const T* __restrict__ cb, float* __restrict__ cnh, float* ps)
{
  int row = blockIdx.x;                  // q*1024 + k
  float v = ldv(cb, (long long)row*256 + threadIdx.x);
  float s = v*v;
  for (int o=32;o>0;o>>=1) s += __shfl_down(s, o, 64);
  if ((threadIdx.x & 63) == 0) ps[threadIdx.x>>6] = s;
  __syncthreads();
  if (threadIdx.x == 0) cnh[row] = 0.5f*(ps[0]+ps[1]+ps[2]+ps[3]);
}

__global__ __launch_bounds__(256) void k_cnh(const void* cb, float* cnh)
{
  __shared__ float ps[4];
  if (sniff_f32(cb)) cnh_impl((const float*)cb, cnh, ps);
  else cnh_impl((const __hip_bfloat16*)cb, cnh, ps);
}

// ============================ VQ argmin (f32) with near-tie flag =============
__global__ __launch_bounds__(256, 2) void k_argmin(const float* __restrict__ resT,
    const float* __restrict__ cbT, const float* __restrict__ cnh,
    int* __restrict__ idxOut, int* __restrict__ flagOut)
{
  __shared__ __align__(16) float lp[2][2048];    // [16 d][128 n]
  __shared__ __align__(16) float lc[2][4096];    // [16 d][256 k]
  const int tid = threadIdx.x;
  const int n0 = blockIdx.x * 128;
  const int tp = tid & 15, tc = tid >> 4;
  const int wave = tid >> 6, lane = tid & 63;
  const float* rbase = resT + n0 + lane;
  const float* cbase = cbT + lane;

  float m1[8], m2[8]; int i1[8];
  #pragma unroll
  for (int i=0;i<8;i++){ m1[i]=INFINITY; m2[i]=INFINITY; i1[i]=0; }

  // prologue: stage (ct=0,dc=0) into buf 0
  #pragma unroll
  for (int r=0;r<4;r++){
    const int dd = wave*4 + r;
    #pragma unroll
    for (int h=0;h<2;h++)
      gl_lds4(rbase + (long long)dd*65536 + h*64, &lp[0][dd*128 + h*64]);
    #pragma unroll
    for (int h=0;h<4;h++)
      gl_lds4(cbase + (long long)dd*1024 + h*64, &lc[0][dd*256 + h*64]);
  }
  __syncthreads();

  float acc[8][16];
  float* lp_c = lp[0]; float* lp_n = lp[1];
  float* lc_c = lc[0]; float* lc_n = lc[1];
  for (int it=0; it<64; ++it){
    const int ct = it>>4, dc = it&15;
    if (dc == 0){
      #pragma unroll
      for (int i=0;i<8;i++)
        #pragma unroll
        for (int j=0;j<16;j++) acc[i][j] = 0.f;
    }
    if (it+1 < 64){
      const int d2 = ((it+1)&15)*16, k2 = ((it+1)>>4)*256;
      #pragma unroll
      for (int r=0;r<4;r++){
        const int dd = wave*4 + r;
        #pragma unroll
        for (int h=0;h<2;h++)
          gl_lds4(rbase + (long long)(d2+dd)*65536 + h*64, lp_n + dd*128 + h*64);
        #pragma unroll
        for (int h=0;h<4;h++)
          gl_lds4(cbase + (long long)(d2+dd)*1024 + k2 + h*64, lc_n + dd*256 + h*64);
      }
    }
    #pragma unroll 4
    for (int dd=0; dd<16; dd++){
      float a[8], c[16];
      *(float4*)&a[0] = *(const float4*)&lp_c[dd*128 + 4*tp];
      *(float4*)&a[4] = *(const float4*)&lp_c[dd*128 + 64 + 4*tp];
      *(float4*)&c[0]  = *(const float4*)&lc_c[dd*256 + 16*tc];
      *(float4*)&c[4]  = *(const float4*)&lc_c[dd*256 + 16*tc + 4];
      *(float4*)&c[8]  = *(const float4*)&lc_c[dd*256 + 16*tc + 8];
      *(float4*)&c[12] = *(const float4*)&lc_c[dd*256 + 16*tc + 12];
      #pragma unroll
      for (int i=0;i<8;i++)
        #pragma unroll
        for (int j=0;j<16;j++) acc[i][j] += a[i]*c[j];
    }
    if (dc == 15){
      const int k0 = ct*256;
      #pragma unroll
      for (int j=0;j<16;j++){
        const int k = k0 + 16*tc + j;
        const float cn = cnh[k];
        #pragma unroll
        for (int i=0;i<8;i++){
          float s = cn - acc[i][j];
          if (s < m1[i]) { m2[i] = m1[i]; m1[i] = s; i1[i] = k; }
          else if (s < m2[i]) m2[i] = s;
        }
      }
    }
    __syncthreads();
    float* t0 = lp_c; lp_c = lp_n; lp_n = t0;
    float* t1 = lc_c; lc_c = lc_n; lc_n = t1;
  }

  // reduce across the 16 tc partitions (overlay onto dead lp/lc)
  float* rm1 = &lc[0][0];           // 128*17 = 2176 floats
  float* rm2 = &lc[0][0] + 2176;    // 2176 floats (spans into lc[1])
  int*   ri1 = (int*)&lp[0][0];     // 2176 ints  (spans into lp[1])
  #pragma unroll
  for (int i=0;i<8;i++){
    const int pnt = (i<4) ? (4*tp + i) : (64 + 4*tp + i - 4);
    rm1[pnt*17 + tc] = m1[i];
    rm2[pnt*17 + tc] = m2[i];
    ri1[pnt*17 + tc] = i1[i];
  }
  __syncthreads();
  if (tid < 128){
    float bm1 = INFINITY, bm2 = INFINITY; int bi = 0;
    for (int t=0;t<16;t++){
      float a = rm1[tid*17+t], b2v = rm2[tid*17+t]; int ia = ri1[tid*17+t];
      if (a < bm1 || (a == bm1 && ia < bi)){ bm2 = fminf(bm1, b2v); bm1 = a; bi = ia; }
      else bm2 = fminf(bm2, fminf(a, b2v));
    }
    idxOut[n0 + tid] = bi;
    float tau = 1e-3f + 1e-5f*fabsf(bm1);
    flagOut[n0 + tid] = (bm2 - bm1 < tau) ? 1 : 0;
  }
}

// ============================ f64 fixup for near-tie points ==================
template<class TCB>
DEVFN void fixup_impl(const float* __restrict__ resT, const TCB* __restrict__ cb,
    long long koff, const int* __restrict__ flags, int* __restrict__ idxOut,
    double* bm, int* bis, float* rsh)
{
  const int tid = threadIdx.x;
  const int n0 = blockIdx.x * 64;
  for (int p=0; p<64; p++){
    int n = n0 + p;
    if (!flags[n]) continue;                 // uniform per block
    rsh[tid] = resT[tid*65536 + n];
    __syncthreads();
    double best = INFINITY; int bidx = 0;
    for (int c=0; c<4; c++){
      int k = tid*4 + c;
      long long base = koff + (long long)k*256;
      double s0=0.0, s1=0.0, s2=0.0, s3=0.0;
      #pragma unroll 8
      for (int d=0; d<256; d+=4){
        double c0 = (double)ldv(cb, base+d);
        double c1 = (double)ldv(cb, base+d+1);
        double c2 = (double)ldv(cb, base+d+2);
        double c3 = (double)ldv(cb, base+d+3);
        s0 += c0*(c0 - 2.0*(double)rsh[d]);
        s1 += c1*(c1 - 2.0*(double)rsh[d+1]);
        s2 += c2*(c2 - 2.0*(double)rsh[d+2]);
        s3 += c3*(c3 - 2.0*(double)rsh[d+3]);
      }
      double s = (s0+s1)+(s2+s3);
      if (s < best || (s == best && k < bidx)){ best = s; bidx = k; }
    }
    bm[tid] = best; bis[tid] = bidx;
    __syncthreads();
    for (int st=128; st>0; st>>=1){
      if (tid < st){
        if (bm[tid+st] < bm[tid] || (bm[tid+st] == bm[tid] && bis[tid+st] < bis[tid])){
          bm[tid] = bm[tid+st]; bis[tid] = bis[tid+st];
        }
      }
      __syncthreads();
    }
    if (tid == 0) idxOut[n] = bis[0];
    __syncthreads();
  }
}

__global__ __launch_bounds__(256) void k_fixup(const float* resT, const void* cb,
    long long koff, const int* flags, int* idxOut)
{
  __shared__ double bm[256]; __shared__ int bis[256];
  __shared__ float rsh[256];
  if (sniff_f32(cb)) fixup_impl(resT, (const float*)cb, koff, flags, idxOut, bm, bis, rsh);
  else fixup_impl(resT, (const __hip_bfloat16*)cb, koff, flags, idxOut, bm, bis, rsh);
}

// ============== VQ update (float4 over n): gather, loss, residual, q-accum ===
template<bool FIRST, class TCB>
DEVFN void update4_impl(const TCB* __restrict__ cb, long long koff,
    const int* __restrict__ idx, float* __restrict__ resT,
    float* __restrict__ qf, float* __restrict__ lossP, float* ps)
{
  int gid = blockIdx.x*256 + threadIdx.x;    // [d][n/4]
  int n = (gid & 16383) * 4, d = gid >> 14;
  int b = n >> 12, hw = n & 4095;
  long long ro = (long long)d*65536 + n;
  float4 r = *(const float4*)&resT[ro];
  int4 iv = *(const int4*)&idx[n];
  float q0 = ldv(cb, koff + (long long)iv.x*256 + d);
  float q1 = ldv(cb, koff + (long long)iv.y*256 + d);
  float q2 = ldv(cb, koff + (long long)iv.z*256 + d);
  float q3 = ldv(cb, koff + (long long)iv.w*256 + d);
  float d0 = q0 - r.x, d1 = q1 - r.y, d2 = q2 - r.z, d3 = q3 - r.w;
  float4 nr; nr.x = -d0; nr.y = -d1; nr.z = -d2; nr.w = -d3;
  *(float4*)&resT[ro] = nr;
  long long qo = (long long)b*1048576 + d*4096 + hw;   // [b][d][hw]
  if (FIRST){
    float4 qv; qv.x = q0; qv.y = q1; qv.z = q2; qv.w = q3;
    *(float4*)&qf[qo] = qv;
  } else {
    float4 old = *(const float4*)&qf[qo];
    float4 qv; qv.x = old.x+q0; qv.y = old.y+q1; qv.z = old.z+q2; qv.w = old.w+q3;
    *(float4*)&qf[qo] = qv;
  }
  float t = d0*d0 + d1*d1 + d2*d2 + d3*d3;
  for (int o=32;o>0;o>>=1) t += __shfl_down(t, o, 64);
  if ((threadIdx.x & 63) == 0) ps[threadIdx.x>>6] = t;
  __syncthreads();
  if (threadIdx.x == 0) lossP[blockIdx.x] = ps[0]+ps[1]+ps[2]+ps[3];
}

template<bool FIRST>
__global__ __launch_bounds__(256) void k_update4(const void* cb, long long koff,
    const int* idx, float* resT, float* qf, float* lossP)
{
  __shared__ float ps[4];
  if (sniff_f32(cb)) update4_impl<FIRST>((const float*)cb, koff, idx, resT, qf, lossP, ps);
  else update4_impl<FIRST>((const __hip_bfloat16*)cb, koff, idx, resT, qf, lossP, ps);
}

__global__ __launch_bounds__(256) void k_lossred(const float* __restrict__ lossP,
    float* __restrict__ outp, int cnt)
{
  double s = 0.0;
  for (int j = threadIdx.x; j < cnt; j += 256) s += (double)lossP[j];
  for (int o=32;o>0;o>>=1) s += __shfl_down(s, o, 64);
  __shared__ double ps[4];
  if ((threadIdx.x & 63) == 0) ps[threadIdx.x>>6] = s;
  __syncthreads();
  if (threadIdx.x == 0) *outp = (float)((ps[0]+ps[1]+ps[2]+ps[3]) / 16777216.0);
}

// ============================ indices writer =================================
__global__ __launch_bounds__(256) void k_write_idx(const int* __restrict__ idxAll,
    float* __restrict__ out)
{
  int gid = blockIdx.x*256 + threadIdx.x;    // ((b*4+q)*4096 + hw)
  int hw = gid & 4095, q = (gid>>12)&3, b = gid>>14;
  out[3145728 + gid] = (float)idxAll[q*65536 + b*4096 + hw];
}

// ===== weight transpose deconv1: [ci128][co64][16] -> [ch32][cc*16+tap][64co]
template<class T>
DEVFN void wtrd_impl(const T* __restrict__ w, const T* __restrict__ bias,
                     float* __restrict__ o)
{
  int gid = blockIdx.x*256 + threadIdx.x;
  if (gid < 131072){
    int co = gid & 63;
    int g6 = gid >> 6;
    int t  = g6 & 63;            // cc*16 + tap
    int ch = g6 >> 6;            // 0..31
    int cc = t >> 4, tap = t & 15;
    int ci = ch*4 + cc;
    float v = ldv(w, ((ci*64 + co)*16 + tap));
    int phys = gid ^ ((tap&1)<<3) ^ ((tap&4)<<2);
    o[phys] = v;
  } else if (gid < 131136){
    o[gid] = ldv(bias, gid - 131072);
  }
}

__global__ __launch_bounds__(256) void k_wtrd(const void* w, const void* bias, float* o)
{
  if (sniff_f32(w)) wtrd_impl((const float*)w, (const float*)bias, o);
  else wtrd_impl((const __hip_bfloat16*)w, (const __hip_bfloat16*)bias, o);
}

// ============================ deconv1: 128->64, 4x4 s2 p1, relu ==============
// Parity sub-convs; epilogue: per-wave LDS transpose (64 rows x stride 36)
// then 8 coalesced float4 stores per lane per half. Values bit-identical.
__global__ __launch_bounds__(256, 4) void k_deconv1n(const float* __restrict__ in,
    const float* __restrict__ wtr, const float* __restrict__ zp,
    float* __restrict__ out)
{
  __shared__ __align__(16) float SM[9280];
  // lin0[512] lin1[512] lw0[4096] lw1[4096] lb[64]; epilogue tile reuses 0..9215
  float* lb = SM + 9216;
  const int tid = threadIdx.x;
  const int tx = blockIdx.x & 3, ty = blockIdx.x >> 2;
  const int b = blockIdx.y;
  if (tid < 64) lb[tid] = wtr[131072 + tid];
  const int pxg = tid & 31, cog = tid >> 5;
  const int xh = pxg & 1, px = (pxg>>1)&1, py = (pxg>>2)&1, yq = pxg>>3;
  const int ox0 = tx*32, oy0 = ty*8, ix0 = tx*16, iy0 = ty*4;
  const int wave = tid >> 6, lane = tid & 63;
  const int wbase = wave*64;

  int goff[2];
  #pragma unroll
  for (int ii=0; ii<2; ii++){
    int j = tid + 256*ii;
    int cc = j / 108, rem = j - cc*108;
    int r = rem / 18, cx = rem - r*18;
    int iy = iy0 - 1 + r, ix = ix0 - 1 + cx;
    bool ok = (j < 432) && ((unsigned)iy < 64u) && ((unsigned)ix < 64u);
    goff[ii] = ok ? (cc*4096 + iy*64 + ix) : -1;
  }
  int wofs[4];
  #pragma unroll
  for (int kyi=0; kyi<2; kyi++)
    #pragma unroll
    for (int kxi=0; kxi<2; kxi++){
      int tap = (1-py+2*kyi)*4 + (1-px) + 2*kxi;
      wofs[kyi*2+kxi] = ((tap*64 + cog*8) ^ ((tap&1)<<3)) ^ ((tap&4)<<2);
    }
  const float* ib0 = in + (long long)b*524288;

  #pragma unroll
  for (int ii=0; ii<2; ii++){
    int wb = wbase + 256*ii;
    if (wb < 432)
      gl_lds4((goff[ii] >= 0) ? (ib0 + goff[ii]) : zp, SM + wb);
  }
  for (int c = wave; c < 16; c += 4)
    gl_lds16(wtr + c*256 + lane*4, SM + 1024 + c*256);
  __syncthreads();

  float acc[8][8];
  #pragma unroll
  for (int i=0;i<8;i++)
    #pragma unroll
    for (int j=0;j<8;j++) acc[i][j] = lb[cog*8+j];

  float* lin_c = SM;        float* lin_n = SM + 512;
  float* lw_c  = SM + 1024; float* lw_n  = SM + 5120;
  for (int k=0; k<32; k++){
    if (k+1 < 32){
      const float* ibk = ib0 + (k+1)*16384;
      const float* wn  = wtr + (k+1)*4096;
      #pragma unroll
      for (int ii=0; ii<2; ii++){
        int wb = wbase + 256*ii;
        if (wb < 432)
          gl_lds4((goff[ii] >= 0) ? (ibk + goff[ii]) : zp, lin_n + wb);
      }
      for (int c = wave; c < 16; c += 4)
        gl_lds16(wn + c*256 + lane*4, lw_n + c*256);
    }
    #pragma unroll 1
    for (int cc=0; cc<4; cc++){
      #pragma unroll
      for (int kyi=0; kyi<2; kyi++){
        const int riy = yq + py + 1 - kyi;
        const float* rowp = &lin_c[(cc*6 + riy)*18 + xh*8];
        float a[10];
        *(float2*)&a[0] = *(const float2*)&rowp[0];
        *(float2*)&a[2] = *(const float2*)&rowp[2];
        *(float2*)&a[4] = *(const float2*)&rowp[4];
        *(float2*)&a[6] = *(const float2*)&rowp[6];
        *(float2*)&a[8] = *(const float2*)&rowp[8];
        #pragma unroll
        for (int kxi=0; kxi<2; kxi++){
          const float* wp = &lw_c[cc*1024 + wofs[kyi*2+kxi]];
          float wv[8];
          *(float4*)&wv[0] = *(const float4*)&wp[0];
          *(float4*)&wv[4] = *(const float4*)&wp[4];
          const int s = 1 + px - kxi;
          #pragma unroll
          for (int j=0;j<8;j++)
            #pragma unroll
            for (int i=0;i<8;i++)
              acc[i][j] += a[i+s]*wv[j];
        }
      }
    }
    __syncthreads();
    float* t0 = lin_c; lin_c = lin_n; lin_n = t0;
    float* t1 = lw_c;  lw_c  = lw_n;  lw_n  = t1;
  }

  // epilogue: per-wave 64x36 tile (write 2-way banks = free), coalesced stores
  float* tile = SM + wave*2304;
  const int cogL = lane >> 5;
  const int oyL = 2*yq + py;
  const long long ob0 = (long long)b*1048576;
  #pragma unroll
  for (int h=0; h<2; h++){
    #pragma unroll
    for (int jp=0; jp<4; jp++){
      const int R = (cogL*4 + jp)*8 + oyL;
      #pragma unroll
      for (int i=0;i<8;i++)
        tile[R*36 + 2*(xh*8+i) + px] = fmaxf(acc[i][h*4+jp], 0.f);
    }
    __syncthreads();
    #pragma unroll
    for (int r=0;r<8;r++){
      const int Q = r*64 + lane;
      const int row = Q >> 3, q = Q & 7;
      const int coRel = row >> 3;                 // 0..7
      const int cgl = coRel >> 2, jp = coRel & 3;
      const int co = (2*wave + cgl)*8 + h*4 + jp;
      const int oy = oy0 + (row & 7);
      float4 v = *(const float4*)&tile[row*36 + 4*q];
      *(float4*)&out[ob0 + (long long)co*16384 + oy*128 + ox0 + 4*q] = v;
    }
    __syncthreads();
  }
}

// ====== weight transpose deconv2: [ci64][co3][16] -> [ch16][cc*16+tap][4co] ==
template<class T>
DEVFN void wtd2_impl(const T* __restrict__ w, const T* __restrict__ bias,
                     float* __restrict__ o)
{
  int gid = blockIdx.x*256 + threadIdx.x;
  if (gid < 4096){
    int co = gid & 3;
    int t2 = gid >> 2;
    int tap = t2 & 15, cc = (t2 >> 4) & 3, ch = t2 >> 6;
    int ci = ch*4 + cc;
    o[gid] = (co < 3) ? ldv(w, (ci*3+co)*16 + tap) : 0.f;
  } else if (gid < 4099){
    o[gid] = ldv(bias, gid - 4096);
  }
}

__global__ __launch_bounds__(256) void k_wtd2(const void* w, const void* bias, float* o)
{
  if (sniff_f32(w)) wtd2_impl((const float*)w, (const float*)bias, o);
  else wtd2_impl((const __hip_bfloat16*)w, (const __hip_bfloat16*)bias, o);
}

// ============================ deconv2: 64->3, 4x4 s2 p1, tanh ================
// Parity sub-convs; epilogue: block-wide 48x68 LDS tile + barrier, coalesced
// float4 stores. Values bit-identical.
__global__ __launch_bounds__(256) void k_deconv2n(const float* __restrict__ in,
    const float* __restrict__ wtr, const float* __restrict__ zp,
    float* __restrict__ outp)
{
  __shared__ __align__(16) float SM[3332];
  // lin0[1408] lin1[1408] lw0[256] lw1[256] lb[4]; epilogue tile reuses 0..3263
  float* lb = SM + 3328;
  const int tid = threadIdx.x;
  const int tx = blockIdx.x & 3, ty = blockIdx.x >> 2;   // input tile 32x8
  const int b = blockIdx.y;
  if (tid < 3) lb[tid] = wtr[4096 + tid];
  if (tid == 3) lb[3] = 0.f;
  const int xq = tid & 7, yl = (tid>>3)&7, px = (tid>>6)&1, py = tid>>7;
  const int x0 = tx*32, y0 = ty*8;
  const int wave = tid >> 6, lane = tid & 63;
  const int wbase = wave*64;

  int goff[6];
  #pragma unroll
  for (int ii=0; ii<6; ii++){
    int j = tid + 256*ii;
    int cc = j / 340, rem = j - cc*340;
    int r = rem / 34, cx = rem - r*34;
    int iy = y0 - 1 + r, ix = x0 - 1 + cx;
    bool ok = (j < 1360) && ((unsigned)iy < 128u) && ((unsigned)ix < 128u);
    goff[ii] = ok ? (cc*16384 + iy*128 + ix) : -1;
  }
  const float* ib0 = in + (long long)b*1048576;          // [64ci][128][128]

  #pragma unroll
  for (int ii=0; ii<6; ii++){
    int wb = wbase + 256*ii;
    if (wb < 1360)
      gl_lds4((goff[ii] >= 0) ? (ib0 + goff[ii]) : zp, SM + wb);
  }
  if (wave == 0)
    gl_lds16(wtr + lane*4, SM + 2816);
  __syncthreads();

  float acc[4][4];
  #pragma unroll
  for (int i=0;i<4;i++)
    #pragma unroll
    for (int j=0;j<4;j++) acc[i][j] = lb[j];

  float* lin_c = SM;        float* lin_n = SM + 1408;
  float* lw_c  = SM + 2816; float* lw_n  = SM + 3072;
  for (int k=0; k<16; k++){
    if (k+1 < 16){
      const float* ibk = ib0 + (k+1)*65536;
      const float* wn  = wtr + (k+1)*256;
      #pragma unroll
      for (int ii=0; ii<6; ii++){
        int wb = wbase + 256*ii;
        if (wb < 1360)
          gl_lds4((goff[ii] >= 0) ? (ibk + goff[ii]) : zp, lin_n + wb);
      }
      if (wave == 0)
        gl_lds16(wn + lane*4, lw_n);
    }
    #pragma unroll 1
    for (int cc=0; cc<4; cc++){
      #pragma unroll
      for (int kyi=0; kyi<2; kyi++){
        const int riy = yl + py + 1 - kyi;
        const float* rowp = &lin_c[(cc*10 + riy)*34 + xq*4];
        float a[6];
        *(float2*)&a[0] = *(const float2*)&rowp[0];
        *(float2*)&a[2] = *(const float2*)&rowp[2];
        *(float2*)&a[4] = *(const float2*)&rowp[4];
        #pragma unroll
        for (int kxi=0; kxi<2; kxi++){
          const int tap = (1-py+2*kyi)*4 + (1-px) + 2*kxi;
          const float* wp = &lw_c[(cc*16 + tap)*4];
          float4 wv = *(const float4*)wp;
          const int s = 1 + px - kxi;
          #pragma unroll
          for (int i=0;i<4;i++){
            acc[i][0] += a[i+s]*wv.x;
            acc[i][1] += a[i+s]*wv.y;
            acc[i][2] += a[i+s]*wv.z;
            acc[i][3] += a[i+s]*wv.w;
          }
        }
      }
    }
    __syncthreads();
    float* t0 = lin_c; lin_c = lin_n; lin_n = t0;
    float* t1 = lw_c;  lw_c  = lw_n;  lw_n  = t1;
  }

  // epilogue: block-wide 48x68 tile, then coalesced float4 stores
  float* tile = SM;
  const int oyL = 2*yl + py;
  #pragma unroll
  for (int j=0;j<3;j++)
    #pragma unroll
    for (int i=0;i<4;i++)
      tile[(j*16 + oyL)*68 + 2*(xq*4+i) + px] = tanhf(acc[i][j]);
  __syncthreads();
  const long long bb = (long long)b*196608;
  #pragma unroll
  for (int r=0;r<3;r++){
    const int Q = r*256 + tid;          // 0..767
    const int row = Q >> 4, q = Q & 15;
    const int co = row >> 4, oy2 = row & 15;
    float4 v = *(const float4*)&tile[row*68 + 4*q];
    *(float4*)&outp[bb + (long long)co*65536 + (2*y0 + oy2)*256 + 2*x0 + 4*q] = v;
  }
}

// ============================ launch =========================================
extern "C" void kernel_launch(void* const* d_in, const int* in_sizes, int n_in,
                              void* d_out, int out_size, void* d_ws, size_t ws_size,
                              hipStream_t stream)
{
  const void* x   = d_in[0];
  const void* w1  = d_in[1];  const void* b1  = d_in[2];
  const void* w2  = d_in[3];  const void* b2  = d_in[4];
  const void* w3  = d_in[5];  const void* b3  = d_in[6];
  const void* w4  = d_in[7];  const void* b4  = d_in[8];
  const void* cb  = d_in[9];
  const void* dw1 = d_in[10]; const void* db1 = d_in[11];
  const void* tw1 = d_in[12]; const void* tb1 = d_in[13];
  const void* tw2 = d_in[14]; const void* tb2 = d_in[15];

  float* out_f  = (float*)d_out;
  float* reconO = out_f;                      // 3,145,728
  float* lossO  = out_f + 3407872;            // 4
  float* qO     = out_f + 3407876;            // 16,777,216  [b][d][hw]

  char* p = (char*)d_ws;
  float* PA   = (float*)p;                     // 64MB: h1 -> h3 -> D1(lower 32MB)
  float* PB   = (float*)(p + 67108864);        // 64MB: h2 -> z/res -> D2
  float* cbT  = (float*)(p + 37748736);        // 4MB  [q][d][k] (post-conv4)
  float* wd2t = (float*)(p + 41943040);        // 16KB (post-conv4)
  float* zp2  = (float*)(p + 41959424);        // 256B zero page (post-conv4)
  float* cnh  = (float*)(p + 50331648);        // 16KB (post-conv4)
  int*   idxB = (int*)  (p + 50348032);        // 1MB
  int*   flg  = (int*)  (p + 51396608);        // 256KB
  float* lossP= (float*)(p + 51658752);        // 256KB (ends < 64MB)

  // Transposed weights + zero-page in dead d_out regions:
  //  - w3t/w4t/w2t in qO (dead until first k_update4)
  //  - d1t/t1t/zp in recon (dead until final k_deconv2n)
  float* w3t = qO;                             // 295,168 f
  float* w4t = qO + 4194304;                   // 590,080 f
  float* w2t = qO + 8388608;                   // 131,200 f
  float* d1t = reconO;                         // 295,040 f
  float* t1t = reconO + 1500000;               // 131,136 f
  float* zp  = reconO + 2500000;               // 64 f

  k_zero<<<1, 64, 0, stream>>>(zp);
  k_wtr<256,128><<<1153, 256, 0, stream>>>(w3,  b3,  w3t);
  k_wtr<256,256><<<2305, 256, 0, stream>>>(w4,  b4,  w4t);
  k_wtr<128,256><<<1153, 256, 0, stream>>>(dw1, db1, d1t);
  k_wtr2<<<513, 256, 0, stream>>>(w2, b2, w2t);
  k_wtrd<<<513, 256, 0, stream>>>(tw1, tb1, t1t);

  k_conv1n<<<dim3(64,16), 256, 0, stream>>>(x, w1, b1, PA);
  k_conv2n<<<dim3(16,16,2), 256, 0, stream>>>(PA, w2t, zp, PB);
  k_conv3x3<128,true ,false><<<dim3(16,16,4), 256, 0, stream>>>(PB, w3t, zp, PA);
  k_conv3x3<256,false,true ><<<dim3(16,16,4), 256, 0, stream>>>(PA, w4t, zp, PB);

  // post-conv4: PA dead except cnh/idx area -> build VQ + decoder-tail consts
  k_cbt<<<dim3(16,4,4), 256, 0, stream>>>(cb, cbT);
  k_cnh<<<4096, 256, 0, stream>>>(cb, cnh);
  k_wtd2<<<17, 256, 0, stream>>>(tw2, tb2, wd2t);
  k_zero<<<1, 64, 0, stream>>>(zp2);

  for (int q=0; q<4; q++){
    long long koff = (long long)q * 262144;
    k_argmin<<<512, 256, 0, stream>>>(PB, cbT + (long long)q*262144,
                                      cnh + q*1024, idxB + q*65536, flg);
    k_fixup <<<1024, 256, 0, stream>>>(PB, cb, koff, flg, idxB + q*65536);
    if (q == 0) k_update4<true ><<<16384, 256, 0, stream>>>(cb, koff, idxB,            PB, qO, lossP);
    else        k_update4<false><<<16384, 256, 0, stream>>>(cb, koff, idxB + q*65536, PB, qO, lossP);
    k_lossred<<<1, 256, 0, stream>>>(lossP, lossO + q, 16384);
  }

  k_write_idx<<<1024, 256, 0, stream>>>(idxB, out_f);

  k_conv3x3<256,true ,false><<<dim3(16,16,2), 256, 0, stream>>>(qO, d1t, zp, PA);
  k_deconv1n<<<dim3(64,16), 256, 0, stream>>>(PA, t1t, zp, PB);
  k_deconv2n<<<dim3(64,16), 256, 0, stream>>>(PB, wd2t, zp2, reconO);
}

// Round 7
// 4996.583 us; speedup vs baseline: 1.1109x; 1.1109x over previous
//
#include <hip/hip_runtime.h>
#include <hip/hip_bf16.h>
#include <math.h>

// ---------------------------------------------------------------------------
// SecretRQVAE. d_out FLOAT32. Inputs runtime-sniffed (bf16 vs f32).
// Outputs (f32): recon[3145728] | indices[262144] | loss[4] | q_chw[16777216]
// Workspace (128 MB): PA [0,64MB): h1 -> h3 -> D1(lower 32MB); small bufs at
// +48MB and cbT/wd2t/zp2 at +36..40MB (live only post-conv4).
// PB [64,128MB): h2 -> z/res [d][n] -> D2.
//
// R11 counters: deconv1n store fix landed (off top-5; WRITE 557->norm), but
// conv3x3 regressed 902->985 (VGPR 72->64, FETCH 317->362MB, occ 27->33%) --
// the R10 launch_bounds(256,4) codegen shift, not a source change. Net flat.
// R12: (a) revert launch_bounds on conv tile kernels to plain (256) = R9
// compile state (902us/VGPR72/FETCH 317MB measured); keep argmin (256,2).
// (b) argmin staging 4B->16B gl_lds16: lp stages 2 rows/instr (per-lane src
// (lane>>5)*65536+(lane&31)*4), lc 1 row/instr; 24->6 VMEM issues/wave/iter.
// LDS contents bit-identical => indices unchanged.
// ---------------------------------------------------------------------------

#define DEVFN static __device__ __forceinline__
DEVFN float b2f(__hip_bfloat16 v){ return __bfloat162float(v); }
DEVFN float ldv(const float* p, long long i){ return p[i]; }
DEVFN float ldv(const __hip_bfloat16* p, long long i){ return b2f(p[i]); }

DEVFN bool sniff_f32(const void* p){
  const unsigned* u = (const unsigned*)p;
  int hits = 0;
  #pragma unroll
  for (int i=0;i<64;i++){
    unsigned b = (u[i]>>7)&0xFFu;
    hits += (b>=118u && b<=134u) ? 1 : 0;
  }
  return hits < 32;
}

// async global->LDS; l must be wave-uniform, g per-lane.
DEVFN void gl_lds16(const float* g, float* l){
  __builtin_amdgcn_global_load_lds(
      (const __attribute__((address_space(1))) void*)g,
      (__attribute__((address_space(3))) void*)l, 16, 0, 0);
}
DEVFN void gl_lds4(const float* g, float* l){
  __builtin_amdgcn_global_load_lds(
      (const __attribute__((address_space(1))) void*)g,
      (__attribute__((address_space(3))) void*)l, 4, 0, 0);
}

// ============================ zero page init ================================
__global__ __launch_bounds__(64) void k_zero(float* zp)
{
  zp[threadIdx.x] = 0.f;
}

// ============================ conv1: 3->64, 4x4 s2 p1, relu ==================
template<class T>
DEVFN void conv1n_impl(const T* __restrict__ x, const T* __restrict__ w,
                       const T* __restrict__ bias, float* __restrict__ out,
                       float* lin, float* lw, float* lb)
{
  const int tid = threadIdx.x;
  const int tx = blockIdx.x & 3, ty = blockIdx.x >> 2;   // 4 x-tiles, 16 y-tiles
  const int b = blockIdx.y;
  for (int j = tid; j < 3072; j += 256){
    int co = j & 63, tt = j >> 6;                        // tt = cc*16+tap
    int cc = tt >> 4, tap = tt & 15;
    lw[j] = ldv(w, (co*3+cc)*16 + tap);
  }
  if (tid < 64) lb[tid] = ldv(bias, tid);
  const int oy0 = ty*8, ox0 = tx*32;
  const int iy0 = 2*oy0 - 1, ix0 = 2*ox0 - 1;
  for (int j = tid; j < 3564; j += 256){                 // 3cc x 18r x 66c
    int cc = j / 1188, rem = j - cc*1188;
    int r = rem / 66, cx = rem - r*66;
    int iy = iy0 + r, ix = ix0 + cx;
    float v = 0.f;
    if ((unsigned)iy < 256u && (unsigned)ix < 256u)
      v = ldv(x, (long long)b*196608 + (cc*256+iy)*256 + ix);
    lin[j] = v;
  }
  __syncthreads();
  const int pxg = tid & 31, cog = tid >> 5;
  const int y = pxg >> 2, xb = (pxg & 3) << 3;
  float acc[8][8];
  #pragma unroll
  for (int i=0;i<8;i++)
    #pragma unroll
    for (int j=0;j<8;j++) acc[i][j] = lb[cog*8+j];
  #pragma unroll 1
  for (int cc=0; cc<3; cc++){
    #pragma unroll
    for (int ky=0; ky<4; ky++){
      const float* rowp = &lin[(cc*18 + 2*y+ky)*66 + 2*xb];
      float a[18];
      #pragma unroll
      for (int t=0; t<9; t++) *(float2*)&a[2*t] = *(const float2*)&rowp[2*t];
      #pragma unroll
      for (int kx=0; kx<4; kx++){
        const float* wp = &lw[(cc*16 + ky*4+kx)*64 + cog*8];
        float wv[8];
        *(float4*)&wv[0] = *(const float4*)&wp[0];
        *(float4*)&wv[4] = *(const float4*)&wp[4];
        #pragma unroll
        for (int j=0;j<8;j++)
          #pragma unroll
          for (int i=0;i<8;i++)
            acc[i][j] += a[2*i+kx]*wv[j];
      }
    }
  }
  #pragma unroll
  for (int j=0;j<8;j++){
    const int co = cog*8 + j;
    float4 v0, v1;
    v0.x = fmaxf(acc[0][j],0.f); v0.y = fmaxf(acc[1][j],0.f);
    v0.z = fmaxf(acc[2][j],0.f); v0.w = fmaxf(acc[3][j],0.f);
    v1.x = fmaxf(acc[4][j],0.f); v1.y = fmaxf(acc[5][j],0.f);
    v1.z = fmaxf(acc[6][j],0.f); v1.w = fmaxf(acc[7][j],0.f);
    long long base = ((long long)(b*64 + co)*128 + oy0+y)*128 + ox0+xb;
    *(float4*)&out[base]   = v0;
    *(float4*)&out[base+4] = v1;
  }
}

__global__ __launch_bounds__(256) void k_conv1n(const void* x, const void* w,
    const void* bias, float* out)
{
  __shared__ __align__(16) float lin[3564];
  __shared__ __align__(16) float lw[3072];
  __shared__ float lb[64];
  if (sniff_f32(w)) conv1n_impl((const float*)x, (const float*)w, (const float*)bias, out, lin, lw, lb);
  else conv1n_impl((const __hip_bfloat16*)x, (const __hip_bfloat16*)w, (const __hip_bfloat16*)bias, out, lin, lw, lb);
}

// ===== weight transpose conv2: [co128][ci64][16] -> [cg2][ch32][cc*16+tap][64co]
template<class T>
DEVFN void wtr2_impl(const T* __restrict__ w, const T* __restrict__ bias,
                     float* __restrict__ o)
{
  int gid = blockIdx.x*256 + threadIdx.x;
  if (gid < 131072){
    int co = gid & 63;
    int g6 = gid >> 6;
    int t  = g6 & 31;            // cc*16 + tap
    int q  = g6 >> 5;            // cg*32 + ch
    int cg = q >> 5, ch = q & 31;
    int cc = t >> 4, tap = t & 15;
    o[gid] = ldv(w, ((cg*64+co)*64 + ch*2+cc)*16 + tap);
  } else if (gid < 131200){
    o[gid] = ldv(bias, gid - 131072);
  }
}

__global__ __launch_bounds__(256) void k_wtr2(const void* w, const void* bias, float* o)
{
  if (sniff_f32(w)) wtr2_impl((const float*)w, (const float*)bias, o);
  else wtr2_impl((const __hip_bfloat16*)w, (const __hip_bfloat16*)bias, o);
}

// ============================ conv2: 64->128, 4x4 s2 p1, relu ================
__global__ __launch_bounds__(256) void k_conv2n(const float* __restrict__ in,
    const float* __restrict__ wtr, const float* __restrict__ zp,
    float* __restrict__ out)
{
  __shared__ __align__(16) float lin[2][2432];   // 2cc x 18r x 66c (+pad)
  __shared__ __align__(16) float lw[2][2048];    // 2cc x 16tap x 64co
  __shared__ float lb[64];
  const int tid = threadIdx.x;
  const int tx = blockIdx.x & 1, ty = blockIdx.x >> 1;
  const int b = blockIdx.y, cg = blockIdx.z;
  if (tid < 64) lb[tid] = wtr[131072 + cg*64 + tid];
  const int pxg = tid & 31, cog = tid >> 5;
  const int y = pxg >> 2, xb = (pxg & 3) << 3;
  const int oy0 = ty*8, ox0 = tx*32;
  const int wave = tid >> 6, lane = tid & 63;
  const int wbase = wave*64;

  int goff[10];
  #pragma unroll
  for (int ii=0; ii<10; ii++){
    int j = tid + 256*ii;
    int cc = j / 1188, rem = j - cc*1188;
    int r = rem / 66, cx = rem - r*66;
    int iy = 2*oy0 - 1 + r, ix = 2*ox0 - 1 + cx;
    bool ok = (j < 2376) && ((unsigned)iy < 128u) && ((unsigned)ix < 128u);
    goff[ii] = ok ? (cc*16384 + iy*128 + ix) : -1;
  }
  const float* ib0 = in + (long long)b*1048576;
  const float* wb0 = wtr + cg*65536;

  #pragma unroll
  for (int ii=0; ii<10; ii++){
    int wb = wbase + 256*ii;
    if (wb < 2376)
      gl_lds4((goff[ii] >= 0) ? (ib0 + goff[ii]) : zp, &lin[0][wb]);
  }
  for (int c = wave; c < 8; c += 4)
    gl_lds16(wb0 + c*256 + lane*4, &lw[0][c*256]);
  __syncthreads();

  float acc[8][8];
  #pragma unroll
  for (int i=0;i<8;i++)
    #pragma unroll
    for (int j=0;j<8;j++) acc[i][j] = lb[cog*8+j];

  float* lin_c = lin[0]; float* lin_n = lin[1];
  float* lw_c  = lw[0];  float* lw_n  = lw[1];
  for (int k=0; k<32; k++){
    if (k+1 < 32){
      const float* ibk = ib0 + (k+1)*32768;
      const float* wn  = wb0 + (k+1)*2048;
      #pragma unroll
      for (int ii=0; ii<10; ii++){
        int wb = wbase + 256*ii;
        if (wb < 2376)
          gl_lds4((goff[ii] >= 0) ? (ibk + goff[ii]) : zp, lin_n + wb);
      }
      for (int c = wave; c < 8; c += 4)
        gl_lds16(wn + c*256 + lane*4, lw_n + c*256);
    }
    #pragma unroll 1
    for (int cc=0; cc<2; cc++){
      #pragma unroll
      for (int ky=0; ky<4; ky++){
        const float* rowp = &lin_c[(cc*18 + 2*y+ky)*66 + 2*xb];
        float a[18];
        #pragma unroll
        for (int t=0; t<9; t++) *(float2*)&a[2*t] = *(const float2*)&rowp[2*t];
        #pragma unroll
        for (int kx=0; kx<4; kx++){
          const float* wp = &lw_c[(cc*16 + ky*4+kx)*64 + cog*8];
          float wv[8];
          *(float4*)&wv[0] = *(const float4*)&wp[0];
          *(float4*)&wv[4] = *(const float4*)&wp[4];
          #pragma unroll
          for (int j=0;j<8;j++)
            #pragma unroll
            for (int i=0;i<8;i++)
              acc[i][j] += a[2*i+kx]*wv[j];
        }
      }
    }
    __syncthreads();
    float* t0 = lin_c; lin_c = lin_n; lin_n = t0;
    float* t1 = lw_c;  lw_c  = lw_n;  lw_n  = t1;
  }

  #pragma unroll
  for (int j=0;j<8;j++){
    const int co = cg*64 + cog*8 + j;
    float4 v0, v1;
    v0.x = fmaxf(acc[0][j],0.f); v0.y = fmaxf(acc[1][j],0.f);
    v0.z = fmaxf(acc[2][j],0.f); v0.w = fmaxf(acc[3][j],0.f);
    v1.x = fmaxf(acc[4][j],0.f); v1.y = fmaxf(acc[5][j],0.f);
    v1.z = fmaxf(acc[6][j],0.f); v1.w = fmaxf(acc[7][j],0.f);
    long long base = ((long long)(b*128 + co)*64 + oy0+y)*64 + ox0+xb;
    *(float4*)&out[base]   = v0;
    *(float4*)&out[base+4] = v1;
  }
}

// ============== weight transpose for 3x3 convs: -> [cg][ch][cc*9+tap][co] ====
template<int CO, int CI, class T>
DEVFN void wtr_impl(const T* __restrict__ w, const T* __restrict__ bias,
                    float* __restrict__ o)
{
  const int NW = CO*CI*9;
  int gid = blockIdx.x*256 + threadIdx.x;
  if (gid < NW){
    int co = gid & 63;
    int g6 = gid >> 6;
    int t  = g6 % 36;            // cc*9 + tap
    int q  = g6 / 36;            // cg*(CI/4) + ch
    const int NCH = CI/4;
    int cg = q / NCH, ch = q - cg*NCH;
    int cc = t / 9, tap = t - cc*9;
    o[gid] = ldv(w, ((long long)(cg*64+co)*CI + ch*4+cc)*9 + tap);
  } else if (gid < NW + CO){
    o[gid] = ldv(bias, gid - NW);
  }
}

template<int CO, int CI>
__global__ __launch_bounds__(256) void k_wtr(const void* w, const void* bias, float* o)
{
  if (sniff_f32(w)) wtr_impl<CO,CI>((const float*)w, (const float*)bias, o);
  else wtr_impl<CO,CI>((const __hip_bfloat16*)w, (const __hip_bfloat16*)bias, o);
}

// ============================ 3x3 s1 p1 conv (conv3/conv4/dec1) =============
template<int CI, bool RELU, bool OUT_T>
__global__ __launch_bounds__(256) void k_conv3x3(const float* __restrict__ in,
    const float* __restrict__ wtr, const float* __restrict__ zp,
    float* __restrict__ out)
{
  __shared__ __align__(16) float lin[2][1408];   // 4cc x 10r x 34c (+tail pad)
  __shared__ __align__(16) float lw[2][2304];    // 4cc x 9tap x 64co
  __shared__ float lb[64];
  const int tid = threadIdx.x;
  const int tx = blockIdx.x & 1, ty = blockIdx.x >> 1;
  const int b = blockIdx.y, cg = blockIdx.z;
  const int CO = gridDim.z * 64;
  const int NCH = CI/4;
  const long long NW = (long long)CO*CI*9;
  if (tid < 64) lb[tid] = wtr[NW + cg*64 + tid];

  const int pxg = tid & 31, cog = tid >> 5;
  const int y = pxg >> 2, xb = (pxg & 3) << 3;
  const int oy0 = ty*8, ox0 = tx*32;
  const int wave = tid >> 6, lane = tid & 63;
  const int wbase = wave*64;

  int goff[6];
  #pragma unroll
  for (int ii=0; ii<6; ii++){
    int j = tid + 256*ii;
    int cc = j / 340, rem = j - cc*340;
    int r = rem / 34, cx = rem - r*34;
    int iy = oy0 - 1 + r, ix = ox0 - 1 + cx;
    bool ok = (j < 1360) && ((unsigned)iy < 64u) && ((unsigned)ix < 64u);
    goff[ii] = ok ? (cc*4096 + iy*64 + ix) : -1;
  }
  const float* ib0 = in + (long long)b*CI*4096;
  const float* wb0 = wtr + (long long)cg*NCH*2304;

  #pragma unroll
  for (int ii=0; ii<6; ii++){
    int wb = wbase + 256*ii;
    if (wb < 1360)
      gl_lds4((goff[ii] >= 0) ? (ib0 + goff[ii]) : zp, &lin[0][wb]);
  }
  for (int c = wave; c < 9; c += 4)
    gl_lds16(wb0 + c*256 + lane*4, &lw[0][c*256]);
  __syncthreads();

  float acc[8][8];
  #pragma unroll
  for (int i=0;i<8;i++)
    #pragma unroll
    for (int j=0;j<8;j++) acc[i][j] = lb[cog*8+j];

  float* lin_c = lin[0]; float* lin_n = lin[1];
  float* lw_c  = lw[0];  float* lw_n  = lw[1];
  for (int k=0; k<NCH; k++){
    if (k+1 < NCH){
      const float* ibk = ib0 + (long long)(k+1)*16384;
      const float* wn  = wb0 + (long long)(k+1)*2304;
      #pragma unroll
      for (int ii=0; ii<6; ii++){
        int wb = wbase + 256*ii;
        if (wb < 1360)
          gl_lds4((goff[ii] >= 0) ? (ibk + goff[ii]) : zp, lin_n + wb);
      }
      for (int c = wave; c < 9; c += 4)
        gl_lds16(wn + c*256 + lane*4, lw_n + c*256);
    }
    #pragma unroll 1
    for (int cc=0; cc<4; cc++){
      #pragma unroll
      for (int dy=0; dy<3; dy++){
        const float* rowp = &lin_c[(cc*10 + y+dy)*34 + xb];
        float a[10];
        *(float2*)&a[0] = *(const float2*)&rowp[0];
        *(float2*)&a[2] = *(const float2*)&rowp[2];
        *(float2*)&a[4] = *(const float2*)&rowp[4];
        *(float2*)&a[6] = *(const float2*)&rowp[6];
        *(float2*)&a[8] = *(const float2*)&rowp[8];
        #pragma unroll
        for (int dx=0; dx<3; dx++){
          const float* wp = &lw_c[(cc*9 + dy*3+dx)*64 + cog*8];
          float wv[8];
          *(float4*)&wv[0] = *(const float4*)&wp[0];
          *(float4*)&wv[4] = *(const float4*)&wp[4];
          #pragma unroll
          for (int j=0;j<8;j++)
            #pragma unroll
            for (int i=0;i<8;i++)
              acc[i][j] += a[i+dx]*wv[j];
        }
      }
    }
    __syncthreads();
    float* t0 = lin_c; lin_c = lin_n; lin_n = t0;
    float* t1 = lw_c;  lw_c  = lw_n;  lw_n  = t1;
  }

  const int oy = oy0 + y;
  #pragma unroll
  for (int j=0;j<8;j++){
    const int co = cg*64 + cog*8 + j;
    float4 v0, v1;
    v0.x = acc[0][j]; v0.y = acc[1][j]; v0.z = acc[2][j]; v0.w = acc[3][j];
    v1.x = acc[4][j]; v1.y = acc[5][j]; v1.z = acc[6][j]; v1.w = acc[7][j];
    if (RELU){
      v0.x = fmaxf(v0.x, 0.f); v0.y = fmaxf(v0.y, 0.f);
      v0.z = fmaxf(v0.z, 0.f); v0.w = fmaxf(v0.w, 0.f);
      v1.x = fmaxf(v1.x, 0.f); v1.y = fmaxf(v1.y, 0.f);
      v1.z = fmaxf(v1.z, 0.f); v1.w = fmaxf(v1.w, 0.f);
    }
    long long base = OUT_T ? ((long long)co*65536 + b*4096 + oy*64 + ox0+xb)
                           : (((long long)(b*CO + co)*64 + oy)*64 + ox0+xb);
    *(float4*)&out[base]   = v0;
    *(float4*)&out[base+4] = v1;
  }
}

// ================= codebook transpose: cb[q][k][d] -> cbT[q][d][k] ==========
template<class T>
DEVFN void cbt_impl(const T* __restrict__ cb, float* __restrict__ o,
                    float (*t)[65])
{
  const int k0 = blockIdx.x*64, d0 = blockIdx.y*64, q = blockIdx.z;
  const int tid = threadIdx.x;
  const int rr = tid >> 6, cc = tid & 63;
  #pragma unroll
  for (int p=0; p<16; p++){
    int kk = p*4 + rr;
    t[kk][cc] = ldv(cb, ((long long)(q*1024 + k0+kk))*256 + d0 + cc);
  }
  __syncthreads();
  #pragma unroll
  for (int p=0; p<16; p++){
    int dd = p*4 + rr;
    o[((long long)(q*256 + d0+dd))*1024 + k0 + cc] = t[cc][dd];
  }
}

__global__ __launch_bounds__(256) void k_cbt(const void* cb, float* o)
{
  __shared__ float t[64][65];
  if (sniff_f32(cb)) cbt_impl((const float*)cb, o, t);
  else cbt_impl((const __hip_bfloat16*)cb, o, t);
}

// ============================ codebook 0.5*||c||^2 ===========================
template<class T>
DEVFN void cnh_impl(const T* __restrict__ cb, float* __restrict__ cnh, float* ps)
{
  int row = blockIdx.x;                  // q*1024 + k
  float v = ldv(cb, (long long)row*256 + threadIdx.x);
  float s = v*v;
  for (int o=32;o>0;o>>=1) s += __shfl_down(s, o, 64);
  if ((threadIdx.x & 63) == 0) ps[threadIdx.x>>6] = s;
  __syncthreads();
  if (threadIdx.x == 0) cnh[row] = 0.5f*(ps[0]+ps[1]+ps[2]+ps[3]);
}

__global__ __launch_bounds__(256) void k_cnh(const void* cb, float* cnh)
{
  __shared__ float ps[4];
  if (sniff_f32(cb)) cnh_impl((const float*)cb, cnh, ps);
  else cnh_impl((const __hip_bfloat16*)cb, cnh, ps);
}

// ============================ VQ argmin (f32) with near-tie flag =============
// 128 points/block (grid 512). Thread = 8 points x 16 codes. 4 ct chunks of
// 256 codes; 16 dc chunks of 16 d. lp/lc dbuf staged async from cbT[d][k]
// via wave-wide gl_lds16: lp 2 rows/instr, lc 1 row/instr (6 VMEM/wave/it).
__global__ __launch_bounds__(256, 2) void k_argmin(const float* __restrict__ resT,
    const float* __restrict__ cbT, const float* __restrict__ cnh,
    int* __restrict__ idxOut, int* __restrict__ flagOut)
{
  __shared__ __align__(16) float lp[2][2048];    // [16 d][128 n]
  __shared__ __align__(16) float lc[2][4096];    // [16 d][256 k]
  const int tid = threadIdx.x;
  const int n0 = blockIdx.x * 128;
  const int tp = tid & 15, tc = tid >> 4;
  const int wave = tid >> 6, lane = tid & 63;
  // lp: one gl_lds16 covers 2 d-rows (512B each); per-lane source offset:
  const long long lpLane = (long long)(lane >> 5)*65536 + (lane & 31)*4;
  const float* rb  = resT + n0;
  const float* cbl = cbT + lane*4;               // lc: 1 row (1KB) per instr

  float m1[8], m2[8]; int i1[8];
  #pragma unroll
  for (int i=0;i<8;i++){ m1[i]=INFINITY; m2[i]=INFINITY; i1[i]=0; }

  // prologue: stage (ct=0,dc=0) into buf 0
  #pragma unroll
  for (int r2=0;r2<2;r2++){
    const int dd = wave*4 + r2*2;
    gl_lds16(rb + (long long)dd*65536 + lpLane, &lp[0][dd*128]);
  }
  #pragma unroll
  for (int r=0;r<4;r++){
    const int dd = wave*4 + r;
    gl_lds16(cbl + (long long)dd*1024, &lc[0][dd*256]);
  }
  __syncthreads();

  float acc[8][16];
  float* lp_c = lp[0]; float* lp_n = lp[1];
  float* lc_c = lc[0]; float* lc_n = lc[1];
  for (int it=0; it<64; ++it){
    const int ct = it>>4, dc = it&15;
    if (dc == 0){
      #pragma unroll
      for (int i=0;i<8;i++)
        #pragma unroll
        for (int j=0;j<16;j++) acc[i][j] = 0.f;
    }
    if (it+1 < 64){
      const int d2 = ((it+1)&15)*16, k2 = ((it+1)>>4)*256;
      #pragma unroll
      for (int r2=0;r2<2;r2++){
        const int dd = wave*4 + r2*2;
        gl_lds16(rb + (long long)(d2+dd)*65536 + lpLane, lp_n + dd*128);
      }
      #pragma unroll
      for (int r=0;r<4;r++){
        const int dd = wave*4 + r;
        gl_lds16(cbl + (long long)(d2+dd)*1024 + k2, lc_n + dd*256);
      }
    }
    #pragma unroll 4
    for (int dd=0; dd<16; dd++){
      float a[8], c[16];
      *(float4*)&a[0] = *(const float4*)&lp_c[dd*128 + 4*tp];
      *(float4*)&a[4] = *(const float4*)&lp_c[dd*128 + 64 + 4*tp];
      *(float4*)&c[0]  = *(const float4*)&lc_c[dd*256 + 16*tc];
      *(float4*)&c[4]  = *(const float4*)&lc_c[dd*256 + 16*tc + 4];
      *(float4*)&c[8]  = *(const float4*)&lc_c[dd*256 + 16*tc + 8];
      *(float4*)&c[12] = *(const float4*)&lc_c[dd*256 + 16*tc + 12];
      #pragma unroll
      for (int i=0;i<8;i++)
        #pragma unroll
        for (int j=0;j<16;j++) acc[i][j] += a[i]*c[j];
    }
    if (dc == 15){
      const int k0 = ct*256;
      #pragma unroll
      for (int j=0;j<16;j++){
        const int k = k0 + 16*tc + j;
        const float cn = cnh[k];
        #pragma unroll
        for (int i=0;i<8;i++){
          float s = cn - acc[i][j];
          if (s < m1[i]) { m2[i] = m1[i]; m1[i] = s; i1[i] = k; }
          else if (s < m2[i]) m2[i] = s;
        }
      }
    }
    __syncthreads();
    float* t0 = lp_c; lp_c = lp_n; lp_n = t0;
    float* t1 = lc_c; lc_c = lc_n; lc_n = t1;
  }

  // reduce across the 16 tc partitions (overlay onto dead lp/lc)
  float* rm1 = &lc[0][0];           // 128*17 = 2176 floats
  float* rm2 = &lc[0][0] + 2176;    // 2176 floats (spans into lc[1])
  int*   ri1 = (int*)&lp[0][0];     // 2176 ints  (spans into lp[1])
  #pragma unroll
  for (int i=0;i<8;i++){
    const int pnt = (i<4) ? (4*tp + i) : (64 + 4*tp + i - 4);
    rm1[pnt*17 + tc] = m1[i];
    rm2[pnt*17 + tc] = m2[i];
    ri1[pnt*17 + tc] = i1[i];
  }
  __syncthreads();
  if (tid < 128){
    float bm1 = INFINITY, bm2 = INFINITY; int bi = 0;
    for (int t=0;t<16;t++){
      float a = rm1[tid*17+t], b2v = rm2[tid*17+t]; int ia = ri1[tid*17+t];
      if (a < bm1 || (a == bm1 && ia < bi)){ bm2 = fminf(bm1, b2v); bm1 = a; bi = ia; }
      else bm2 = fminf(bm2, fminf(a, b2v));
    }
    idxOut[n0 + tid] = bi;
    float tau = 1e-3f + 1e-5f*fabsf(bm1);
    flagOut[n0 + tid] = (bm2 - bm1 < tau) ? 1 : 0;
  }
}

// ============================ f64 fixup for near-tie points ==================
template<class TCB>
DEVFN void fixup_impl(const float* __restrict__ resT, const TCB* __restrict__ cb,
    long long koff, const int* __restrict__ flags, int* __restrict__ idxOut,
    double* bm, int* bis, float* rsh)
{
  const int tid = threadIdx.x;
  const int n0 = blockIdx.x * 64;
  for (int p=0; p<64; p++){
    int n = n0 + p;
    if (!flags[n]) continue;                 // uniform per block
    rsh[tid] = resT[tid*65536 + n];
    __syncthreads();
    double best = INFINITY; int bidx = 0;
    for (int c=0; c<4; c++){
      int k = tid*4 + c;
      long long base = koff + (long long)k*256;
      double s0=0.0, s1=0.0, s2=0.0, s3=0.0;
      #pragma unroll 8
      for (int d=0; d<256; d+=4){
        double c0 = (double)ldv(cb, base+d);
        double c1 = (double)ldv(cb, base+d+1);
        double c2 = (double)ldv(cb, base+d+2);
        double c3 = (double)ldv(cb, base+d+3);
        s0 += c0*(c0 - 2.0*(double)rsh[d]);
        s1 += c1*(c1 - 2.0*(double)rsh[d+1]);
        s2 += c2*(c2 - 2.0*(double)rsh[d+2]);
        s3 += c3*(c3 - 2.0*(double)rsh[d+3]);
      }
      double s = (s0+s1)+(s2+s3);
      if (s < best || (s == best && k < bidx)){ best = s; bidx = k; }
    }
    bm[tid] = best; bis[tid] = bidx;
    __syncthreads();
    for (int st=128; st>0; st>>=1){
      if (tid < st){
        if (bm[tid+st] < bm[tid] || (bm[tid+st] == bm[tid] && bis[tid+st] < bis[tid])){
          bm[tid] = bm[tid+st]; bis[tid] = bis[tid+st];
        }
      }
      __syncthreads();
    }
    if (tid == 0) idxOut[n] = bis[0];
    __syncthreads();
  }
}

__global__ __launch_bounds__(256) void k_fixup(const float* resT, const void* cb,
    long long koff, const int* flags, int* idxOut)
{
  __shared__ double bm[256]; __shared__ int bis[256];
  __shared__ float rsh[256];
  if (sniff_f32(cb)) fixup_impl(resT, (const float*)cb, koff, flags, idxOut, bm, bis, rsh);
  else fixup_impl(resT, (const __hip_bfloat16*)cb, koff, flags, idxOut, bm, bis, rsh);
}

// ============== VQ update (float4 over n): gather, loss, residual, q-accum ===
template<bool FIRST, class TCB>
DEVFN void update4_impl(const TCB* __restrict__ cb, long long koff,
    const int* __restrict__ idx, float* __restrict__ resT,
    float* __restrict__ qf, float* __restrict__ lossP, float* ps)
{
  int gid = blockIdx.x*256 + threadIdx.x;    // [d][n/4]
  int n = (gid & 16383) * 4, d = gid >> 14;
  int b = n >> 12, hw = n & 4095;
  long long ro = (long long)d*65536 + n;
  float4 r = *(const float4*)&resT[ro];
  int4 iv = *(const int4*)&idx[n];
  float q0 = ldv(cb, koff + (long long)iv.x*256 + d);
  float q1 = ldv(cb, koff + (long long)iv.y*256 + d);
  float q2 = ldv(cb, koff + (long long)iv.z*256 + d);
  float q3 = ldv(cb, koff + (long long)iv.w*256 + d);
  float d0 = q0 - r.x, d1 = q1 - r.y, d2 = q2 - r.z, d3 = q3 - r.w;
  float4 nr; nr.x = -d0; nr.y = -d1; nr.z = -d2; nr.w = -d3;
  *(float4*)&resT[ro] = nr;
  long long qo = (long long)b*1048576 + d*4096 + hw;   // [b][d][hw]
  if (FIRST){
    float4 qv; qv.x = q0; qv.y = q1; qv.z = q2; qv.w = q3;
    *(float4*)&qf[qo] = qv;
  } else {
    float4 old = *(const float4*)&qf[qo];
    float4 qv; qv.x = old.x+q0; qv.y = old.y+q1; qv.z = old.z+q2; qv.w = old.w+q3;
    *(float4*)&qf[qo] = qv;
  }
  float t = d0*d0 + d1*d1 + d2*d2 + d3*d3;
  for (int o=32;o>0;o>>=1) t += __shfl_down(t, o, 64);
  if ((threadIdx.x & 63) == 0) ps[threadIdx.x>>6] = t;
  __syncthreads();
  if (threadIdx.x == 0) lossP[blockIdx.x] = ps[0]+ps[1]+ps[2]+ps[3];
}

template<bool FIRST>
__global__ __launch_bounds__(256) void k_update4(const void* cb, long long koff,
    const int* idx, float* resT, float* qf, float* lossP)
{
  __shared__ float ps[4];
  if (sniff_f32(cb)) update4_impl<FIRST>((const float*)cb, koff, idx, resT, qf, lossP, ps);
  else update4_impl<FIRST>((const __hip_bfloat16*)cb, koff, idx, resT, qf, lossP, ps);
}

__global__ __launch_bounds__(256) void k_lossred(const float* __restrict__ lossP,
    float* __restrict__ outp, int cnt)
{
  double s = 0.0;
  for (int j = threadIdx.x; j < cnt; j += 256) s += (double)lossP[j];
  for (int o=32;o>0;o>>=1) s += __shfl_down(s, o, 64);
  __shared__ double ps[4];
  if ((threadIdx.x & 63) == 0) ps[threadIdx.x>>6] = s;
  __syncthreads();
  if (threadIdx.x == 0) *outp = (float)((ps[0]+ps[1]+ps[2]+ps[3]) / 16777216.0);
}

// ============================ indices writer =================================
__global__ __launch_bounds__(256) void k_write_idx(const int* __restrict__ idxAll,
    float* __restrict__ out)
{
  int gid = blockIdx.x*256 + threadIdx.x;    // ((b*4+q)*4096 + hw)
  int hw = gid & 4095, q = (gid>>12)&3, b = gid>>14;
  out[3145728 + gid] = (float)idxAll[q*65536 + b*4096 + hw];
}

// ===== weight transpose deconv1: [ci128][co64][16] -> [ch32][cc*16+tap][64co]
template<class T>
DEVFN void wtrd_impl(const T* __restrict__ w, const T* __restrict__ bias,
                     float* __restrict__ o)
{
  int gid = blockIdx.x*256 + threadIdx.x;
  if (gid < 131072){
    int co = gid & 63;
    int g6 = gid >> 6;
    int t  = g6 & 63;            // cc*16 + tap
    int ch = g6 >> 6;            // 0..31
    int cc = t >> 4, tap = t & 15;
    int ci = ch*4 + cc;
    float v = ldv(w, ((ci*64 + co)*16 + tap));
    int phys = gid ^ ((tap&1)<<3) ^ ((tap&4)<<2);
    o[phys] = v;
  } else if (gid < 131136){
    o[gid] = ldv(bias, gid - 131072);
  }
}

__global__ __launch_bounds__(256) void k_wtrd(const void* w, const void* bias, float* o)
{
  if (sniff_f32(w)) wtrd_impl((const float*)w, (const float*)bias, o);
  else wtrd_impl((const __hip_bfloat16*)w, (const __hip_bfloat16*)bias, o);
}

// ============================ deconv1: 128->64, 4x4 s2 p1, relu ==============
// Parity sub-convs; epilogue: per-wave LDS transpose (64 rows x stride 36)
// then 8 coalesced float4 stores per lane per half. Values bit-identical.
__global__ __launch_bounds__(256) void k_deconv1n(const float* __restrict__ in,
    const float* __restrict__ wtr, const float* __restrict__ zp,
    float* __restrict__ out)
{
  __shared__ __align__(16) float SM[9280];
  // lin0[512] lin1[512] lw0[4096] lw1[4096] lb[64]; epilogue tile reuses 0..9215
  float* lb = SM + 9216;
  const int tid = threadIdx.x;
  const int tx = blockIdx.x & 3, ty = blockIdx.x >> 2;
  const int b = blockIdx.y;
  if (tid < 64) lb[tid] = wtr[131072 + tid];
  const int pxg = tid & 31, cog = tid >> 5;
  const int xh = pxg & 1, px = (pxg>>1)&1, py = (pxg>>2)&1, yq = pxg>>3;
  const int ox0 = tx*32, oy0 = ty*8, ix0 = tx*16, iy0 = ty*4;
  const int wave = tid >> 6, lane = tid & 63;
  const int wbase = wave*64;

  int goff[2];
  #pragma unroll
  for (int ii=0; ii<2; ii++){
    int j = tid + 256*ii;
    int cc = j / 108, rem = j - cc*108;
    int r = rem / 18, cx = rem - r*18;
    int iy = iy0 - 1 + r, ix = ix0 - 1 + cx;
    bool ok = (j < 432) && ((unsigned)iy < 64u) && ((unsigned)ix < 64u);
    goff[ii] = ok ? (cc*4096 + iy*64 + ix) : -1;
  }
  int wofs[4];
  #pragma unroll
  for (int kyi=0; kyi<2; kyi++)
    #pragma unroll
    for (int kxi=0; kxi<2; kxi++){
      int tap = (1-py+2*kyi)*4 + (1-px) + 2*kxi;
      wofs[kyi*2+kxi] = ((tap*64 + cog*8) ^ ((tap&1)<<3)) ^ ((tap&4)<<2);
    }
  const float* ib0 = in + (long long)b*524288;

  #pragma unroll
  for (int ii=0; ii<2; ii++){
    int wb = wbase + 256*ii;
    if (wb < 432)
      gl_lds4((goff[ii] >= 0) ? (ib0 + goff[ii]) : zp, SM + wb);
  }
  for (int c = wave; c < 16; c += 4)
    gl_lds16(wtr + c*256 + lane*4, SM + 1024 + c*256);
  __syncthreads();

  float acc[8][8];
  #pragma unroll
  for (int i=0;i<8;i++)
    #pragma unroll
    for (int j=0;j<8;j++) acc[i][j] = lb[cog*8+j];

  float* lin_c = SM;        float* lin_n = SM + 512;
  float* lw_c  = SM + 1024; float* lw_n  = SM + 5120;
  for (int k=0; k<32; k++){
    if (k+1 < 32){
      const float* ibk = ib0 + (k+1)*16384;
      const float* wn  = wtr + (k+1)*4096;
      #pragma unroll
      for (int ii=0; ii<2; ii++){
        int wb = wbase + 256*ii;
        if (wb < 432)
          gl_lds4((goff[ii] >= 0) ? (ibk + goff[ii]) : zp, lin_n + wb);
      }
      for (int c = wave; c < 16; c += 4)
        gl_lds16(wn + c*256 + lane*4, lw_n + c*256);
    }
    #pragma unroll 1
    for (int cc=0; cc<4; cc++){
      #pragma unroll
      for (int kyi=0; kyi<2; kyi++){
        const int riy = yq + py + 1 - kyi;
        const float* rowp = &lin_c[(cc*6 + riy)*18 + xh*8];
        float a[10];
        *(float2*)&a[0] = *(const float2*)&rowp[0];
        *(float2*)&a[2] = *(const float2*)&rowp[2];
        *(float2*)&a[4] = *(const float2*)&rowp[4];
        *(float2*)&a[6] = *(const float2*)&rowp[6];
        *(float2*)&a[8] = *(const float2*)&rowp[8];
        #pragma unroll
        for (int kxi=0; kxi<2; kxi++){
          const float* wp = &lw_c[cc*1024 + wofs[kyi*2+kxi]];
          float wv[8];
          *(float4*)&wv[0] = *(const float4*)&wp[0];
          *(float4*)&wv[4] = *(const float4*)&wp[4];
          const int s = 1 + px - kxi;
          #pragma unroll
          for (int j=0;j<8;j++)
            #pragma unroll
            for (int i=0;i<8;i++)
              acc[i][j] += a[i+s]*wv[j];
        }
      }
    }
    __syncthreads();
    float* t0 = lin_c; lin_c = lin_n; lin_n = t0;
    float* t1 = lw_c;  lw_c  = lw_n;  lw_n  = t1;
  }

  // epilogue: per-wave 64x36 tile (write 2-way banks = free), coalesced stores
  float* tile = SM + wave*2304;
  const int cogL = lane >> 5;
  const int oyL = 2*yq + py;
  const long long ob0 = (long long)b*1048576;
  #pragma unroll
  for (int h=0; h<2; h++){
    #pragma unroll
    for (int jp=0; jp<4; jp++){
      const int R = (cogL*4 + jp)*8 + oyL;
      #pragma unroll
      for (int i=0;i<8;i++)
        tile[R*36 + 2*(xh*8+i) + px] = fmaxf(acc[i][h*4+jp], 0.f);
    }
    __syncthreads();
    #pragma unroll
    for (int r=0;r<8;r++){
      const int Q = r*64 + lane;
      const int row = Q >> 3, q = Q & 7;
      const int coRel = row >> 3;                 // 0..7
      const int cgl = coRel >> 2, jp = coRel & 3;
      const int co = (2*wave + cgl)*8 + h*4 + jp;
      const int oy = oy0 + (row & 7);
      float4 v = *(const float4*)&tile[row*36 + 4*q];
      *(float4*)&out[ob0 + (long long)co*16384 + oy*128 + ox0 + 4*q] = v;
    }
    __syncthreads();
  }
}

// ====== weight transpose deconv2: [ci64][co3][16] -> [ch16][cc*16+tap][4co] ==
template<class T>
DEVFN void wtd2_impl(const T* __restrict__ w, const T* __restrict__ bias,
                     float* __restrict__ o)
{
  int gid = blockIdx.x*256 + threadIdx.x;
  if (gid < 4096){
    int co = gid & 3;
    int t2 = gid >> 2;
    int tap = t2 & 15, cc = (t2 >> 4) & 3, ch = t2 >> 6;
    int ci = ch*4 + cc;
    o[gid] = (co < 3) ? ldv(w, (ci*3+co)*16 + tap) : 0.f;
  } else if (gid < 4099){
    o[gid] = ldv(bias, gid - 4096);
  }
}

__global__ __launch_bounds__(256) void k_wtd2(const void* w, const void* bias, float* o)
{
  if (sniff_f32(w)) wtd2_impl((const float*)w, (const float*)bias, o);
  else wtd2_impl((const __hip_bfloat16*)w, (const __hip_bfloat16*)bias, o);
}

// ============================ deconv2: 64->3, 4x4 s2 p1, tanh ================
// Parity sub-convs; epilogue: block-wide 48x68 LDS tile + barrier, coalesced
// float4 stores. Values bit-identical.
__global__ __launch_bounds__(256) void k_deconv2n(const float* __restrict__ in,
    const float* __restrict__ wtr, const float* __restrict__ zp,
    float* __restrict__ outp)
{
  __shared__ __align__(16) float SM[3332];
  // lin0[1408] lin1[1408] lw0[256] lw1[256] lb[4]; epilogue tile reuses 0..3263
  float* lb = SM + 3328;
  const int tid = threadIdx.x;
  const int tx = blockIdx.x & 3, ty = blockIdx.x >> 2;   // input tile 32x8
  const int b = blockIdx.y;
  if (tid < 3) lb[tid] = wtr[4096 + tid];
  if (tid == 3) lb[3] = 0.f;
  const int xq = tid & 7, yl = (tid>>3)&7, px = (tid>>6)&1, py = tid>>7;
  const int x0 = tx*32, y0 = ty*8;
  const int wave = tid >> 6, lane = tid & 63;
  const int wbase = wave*64;

  int goff[6];
  #pragma unroll
  for (int ii=0; ii<6; ii++){
    int j = tid + 256*ii;
    int cc = j / 340, rem = j - cc*340;
    int r = rem / 34, cx = rem - r*34;
    int iy = y0 - 1 + r, ix = x0 - 1 + cx;
    bool ok = (j < 1360) && ((unsigned)iy < 128u) && ((unsigned)ix < 128u);
    goff[ii] = ok ? (cc*16384 + iy*128 + ix) : -1;
  }
  const float* ib0 = in + (long long)b*1048576;          // [64ci][128][128]

  #pragma unroll
  for (int ii=0; ii<6; ii++){
    int wb = wbase + 256*ii;
    if (wb < 1360)
      gl_lds4((goff[ii] >= 0) ? (ib0 + goff[ii]) : zp, SM + wb);
  }
  if (wave == 0)
    gl_lds16(wtr + lane*4, SM + 2816);
  __syncthreads();

  float acc[4][4];
  #pragma unroll
  for (int i=0;i<4;i++)
    #pragma unroll
    for (int j=0;j<4;j++) acc[i][j] = lb[j];

  float* lin_c = SM;        float* lin_n = SM + 1408;
  float* lw_c  = SM + 2816; float* lw_n  = SM + 3072;
  for (int k=0; k<16; k++){
    if (k+1 < 16){
      const float* ibk = ib0 + (k+1)*65536;
      const float* wn  = wtr + (k+1)*256;
      #pragma unroll
      for (int ii=0; ii<6; ii++){
        int wb = wbase + 256*ii;
        if (wb < 1360)
          gl_lds4((goff[ii] >= 0) ? (ibk + goff[ii]) : zp, lin_n + wb);
      }
      if (wave == 0)
        gl_lds16(wn + lane*4, lw_n);
    }
    #pragma unroll 1
    for (int cc=0; cc<4; cc++){
      #pragma unroll
      for (int kyi=0; kyi<2; kyi++){
        const int riy = yl + py + 1 - kyi;
        const float* rowp = &lin_c[(cc*10 + riy)*34 + xq*4];
        float a[6];
        *(float2*)&a[0] = *(const float2*)&rowp[0];
        *(float2*)&a[2] = *(const float2*)&rowp[2];
        *(float2*)&a[4] = *(const float2*)&rowp[4];
        #pragma unroll
        for (int kxi=0; kxi<2; kxi++){
          const int tap = (1-py+2*kyi)*4 + (1-px) + 2*kxi;
          const float* wp = &lw_c[(cc*16 + tap)*4];
          float4 wv = *(const float4*)wp;
          const int s = 1 + px - kxi;
          #pragma unroll
          for (int i=0;i<4;i++){
            acc[i][0] += a[i+s]*wv.x;
            acc[i][1] += a[i+s]*wv.y;
            acc[i][2] += a[i+s]*wv.z;
            acc[i][3] += a[i+s]*wv.w;
          }
        }
      }
    }
    __syncthreads();
    float* t0 = lin_c; lin_c = lin_n; lin_n = t0;
    float* t1 = lw_c;  lw_c  = lw_n;  lw_n  = t1;
  }

  // epilogue: block-wide 48x68 tile, then coalesced float4 stores
  float* tile = SM;
  const int oyL = 2*yl + py;
  #pragma unroll
  for (int j=0;j<3;j++)
    #pragma unroll
    for (int i=0;i<4;i++)
      tile[(j*16 + oyL)*68 + 2*(xq*4+i) + px] = tanhf(acc[i][j]);
  __syncthreads();
  const long long bb = (long long)b*196608;
  #pragma unroll
  for (int r=0;r<3;r++){
    const int Q = r*256 + tid;          // 0..767
    const int row = Q >> 4, q = Q & 15;
    const int co = row >> 4, oy2 = row & 15;
    float4 v = *(const float4*)&tile[row*68 + 4*q];
    *(float4*)&outp[bb + (long long)co*65536 + (2*y0 + oy2)*256 + 2*x0 + 4*q] = v;
  }
}

// ============================ launch =========================================
extern "C" void kernel_launch(void* const* d_in, const int* in_sizes, int n_in,
                              void* d_out, int out_size, void* d_ws, size_t ws_size,
                              hipStream_t stream)
{
  const void* x   = d_in[0];
  const void* w1  = d_in[1];  const void* b1  = d_in[2];
  const void* w2  = d_in[3];  const void* b2  = d_in[4];
  const void* w3  = d_in[5];  const void* b3  = d_in[6];
  const void* w4  = d_in[7];  const void* b4  = d_in[8];
  const void* cb  = d_in[9];
  const void* dw1 = d_in[10]; const void* db1 = d_in[11];
  const void* tw1 = d_in[12]; const void* tb1 = d_in[13];
  const void* tw2 = d_in[14]; const void* tb2 = d_in[15];

  float* out_f  = (float*)d_out;
  float* reconO = out_f;                      // 3,145,728
  float* lossO  = out_f + 3407872;            // 4
  float* qO     = out_f + 3407876;            // 16,777,216  [b][d][hw]

  char* p = (char*)d_ws;
  float* PA   = (float*)p;                     // 64MB: h1 -> h3 -> D1(lower 32MB)
  float* PB   = (float*)(p + 67108864);        // 64MB: h2 -> z/res -> D2
  float* cbT  = (float*)(p + 37748736);        // 4MB  [q][d][k] (post-conv4)
  float* wd2t = (float*)(p + 41943040);        // 16KB (post-conv4)
  float* zp2  = (float*)(p + 41959424);        // 256B zero page (post-conv4)
  float* cnh  = (float*)(p + 50331648);        // 16KB (post-conv4)
  int*   idxB = (int*)  (p + 50348032);        // 1MB
  int*   flg  = (int*)  (p + 51396608);        // 256KB
  float* lossP= (float*)(p + 51658752);        // 256KB (ends < 64MB)

  // Transposed weights + zero-page in dead d_out regions:
  //  - w3t/w4t/w2t in qO (dead until first k_update4)
  //  - d1t/t1t/zp in recon (dead until final k_deconv2n)
  float* w3t = qO;                             // 295,168 f
  float* w4t = qO + 4194304;                   // 590,080 f
  float* w2t = qO + 8388608;                   // 131,200 f
  float* d1t = reconO;                         // 295,040 f
  float* t1t = reconO + 1500000;               // 131,136 f
  float* zp  = reconO + 2500000;               // 64 f

  k_zero<<<1, 64, 0, stream>>>(zp);
  k_wtr<256,128><<<1153, 256, 0, stream>>>(w3,  b3,  w3t);
  k_wtr<256,256><<<2305, 256, 0, stream>>>(w4,  b4,  w4t);
  k_wtr<128,256><<<1153, 256, 0, stream>>>(dw1, db1, d1t);
  k_wtr2<<<513, 256, 0, stream>>>(w2, b2, w2t);
  k_wtrd<<<513, 256, 0, stream>>>(tw1, tb1, t1t);

  k_conv1n<<<dim3(64,16), 256, 0, stream>>>(x, w1, b1, PA);
  k_conv2n<<<dim3(16,16,2), 256, 0, stream>>>(PA, w2t, zp, PB);
  k_conv3x3<128,true ,false><<<dim3(16,16,4), 256, 0, stream>>>(PB, w3t, zp, PA);
  k_conv3x3<256,false,true ><<<dim3(16,16,4), 256, 0, stream>>>(PA, w4t, zp, PB);

  // post-conv4: PA dead except cnh/idx area -> build VQ + decoder-tail consts
  k_cbt<<<dim3(16,4,4), 256, 0, stream>>>(cb, cbT);
  k_cnh<<<4096, 256, 0, stream>>>(cb, cnh);
  k_wtd2<<<17, 256, 0, stream>>>(tw2, tb2, wd2t);
  k_zero<<<1, 64, 0, stream>>>(zp2);

  for (int q=0; q<4; q++){
    long long koff = (long long)q * 262144;
    k_argmin<<<512, 256, 0, stream>>>(PB, cbT + (long long)q*262144,
                                      cnh + q*1024, idxB + q*65536, flg);
    k_fixup <<<1024, 256, 0, stream>>>(PB, cb, koff, flg, idxB + q*65536);
    if (q == 0) k_update4<true ><<<16384, 256, 0, stream>>>(cb, koff, idxB,            PB, qO, lossP);
    else        k_update4<false><<<16384, 256, 0, stream>>>(cb, koff, idxB + q*65536, PB, qO, lossP);
    k_lossred<<<1, 256, 0, stream>>>(lossP, lossO + q, 16384);
  }

  k_write_idx<<<1024, 256, 0, stream>>>(idxB, out_f);

  k_conv3x3<256,true ,false><<<dim3(16,16,2), 256, 0, stream>>>(qO, d1t, zp, PA);
  k_deconv1n<<<dim3(64,16), 256, 0, stream>>>(PA, t1t, zp, PB);
  k_deconv2n<<<dim3(64,16), 256, 0, stream>>>(PB, wd2t, zp2, reconO);
}